// Round 9
// baseline (424.635 us; speedup 1.0000x reference)
//
#include <hip/hip_runtime.h>
#include <stdint.h>
#include <type_traits>

typedef __bf16 bf16;
typedef _Float16 f16;
typedef bf16 bf16x8 __attribute__((ext_vector_type(8)));
typedef f16 f16x8 __attribute__((ext_vector_type(8)));
typedef float f32x4 __attribute__((ext_vector_type(4)));

#define LOG2E 1.4426950408889634f
#define SQRT_E 27.712812921102035f

enum { EPI_F32 = 0, EPI_PAIR = 1, EPI_VT = 2, EPI_F16 = 3 };

__device__ __forceinline__ void async16(const void* g, void* l) {
  __builtin_amdgcn_global_load_lds(
      (__attribute__((address_space(1))) void*)(uintptr_t)g,
      (__attribute__((address_space(3))) void*)l, 16, 0, 0);
}

__device__ __forceinline__ f32x4 mfma8(bf16x8 a, bf16x8 b, f32x4 c) {
  return __builtin_amdgcn_mfma_f32_16x16x32_bf16(a, b, c, 0, 0, 0);
}
__device__ __forceinline__ f32x4 mfma8(f16x8 a, f16x8 b, f32x4 c) {
  return __builtin_amdgcn_mfma_f32_16x16x32_f16(a, b, c, 0, 0, 0);
}

template <int N>
__device__ __forceinline__ void vwait() {
  asm volatile("s_waitcnt vmcnt(%0)" ::"i"(N) : "memory");
}
__device__ __forceinline__ void block_bar() {
  asm volatile("" ::: "memory");
  __builtin_amdgcn_s_barrier();
  asm volatile("" ::: "memory");
}
__device__ __forceinline__ void lgkm0() {
  asm volatile("s_waitcnt lgkmcnt(0)" ::: "memory");
}
__device__ __forceinline__ void spin() { __builtin_amdgcn_sched_barrier(0); }

// ---------------------------------------------------------------------------
// S kernel: 256x256 ring GEMM (round-3/8 verified K-loop, static x3 unroll).
// Stores RAW fp32 scores via the round-3 VERIFIED path (WRITE ~= ideal), then
// tile-softmax stats sidecar (round-4/8 verified math, acc NOT mutated):
//   m_t[row] = max over this N-tile's 256 cols ; sum_t[row] = sum exp(s-m_t)
//   -> mxg/smg [z][tile][2048]  (2 MB each)
// z-major XCD decode: one batch per XCD (FETCH 110->37MB HW-verified).
// ---------------------------------------------------------------------------
__global__ __launch_bounds__(512, 2)
void s_ring(const f16* __restrict__ Ah, const f16* __restrict__ Bh,
            float* __restrict__ Sc, float* __restrict__ mxg,
            float* __restrict__ smg) {
  __shared__ __align__(16) char smem[98304];
  f16* sAb = (f16*)smem;
  f16* sBb = (f16*)(smem + 49152);

  const int id = blockIdx.x;
  const int xcd = id & 7;
  const int j0 = id >> 3;
  const int s = j0 >> 3;
  const int bxi = j0 & 7;
  const int g = xcd + 8 * s;
  const int z = g & 7;       // one batch per XCD
  const int byi = g >> 3;

  const f16* pA = Ah + (long)z * 1572864;
  const f16* pB = Bh + (long)z * 1572864;

  const int bm = byi * 256;
  const int bn = bxi * 256;
  const int tid = threadIdx.x;
  const int wave = tid >> 6;
  const int lane = tid & 63;
  const int wm = (wave >> 2) * 128;
  const int wn = (wave & 3) * 64;
  const int quad = lane >> 4;
  const int l16 = lane & 15;

  f32x4 acc[8][4] = {};

  const int srow = tid >> 2;
  const int swc = ((tid & 3) ^ ((tid >> 3) & 3)) * 8;   // BK32 chunk swizzle
  const int cread = (quad ^ ((l16 >> 1) & 3)) * 8;

  constexpr int NT = 24;   // K=768 / 32
  constexpr int LPT = 4;

  auto stageA = [&](int buf, int t, int l) {
    const long ka = (long)t * 32 + swc;
    async16(pA + (long)(bm + l * 128 + srow) * 768 + ka,
            &sAb[buf * 8192 + (l * 512 + tid) * 8]);
  };
  auto stageB = [&](int buf, int t, int l) {
    const long ka = (long)t * 32 + swc;
    async16(pB + (long)(bn + l * 128 + srow) * 768 + ka,
            &sBb[buf * 8192 + (l * 512 + tid) * 8]);
  };

  stageA(0, 0, 0); stageA(0, 0, 1); stageB(0, 0, 0); stageB(0, 0, 1);
  stageA(1, 1, 0); stageA(1, 1, 1); stageB(1, 1, 0); stageB(1, 1, 1);
  vwait<LPT>();
  block_bar();

  auto tile_step = [&](int t, int cur, int b2) {
    const bool st = (t + 2 < NT);
    f16x8 bfr[4], af[4];
#pragma unroll
    for (int j = 0; j < 4; ++j)
      bfr[j] = *(const f16x8*)&sBb[cur * 8192 + (wn + j * 16 + l16) * 32 + cread];
#pragma unroll
    for (int i = 0; i < 4; ++i)
      af[i] = *(const f16x8*)&sAb[cur * 8192 + (wm + i * 16 + l16) * 32 + cread];
    if (st) { stageA(b2, t + 2, 0); stageA(b2, t + 2, 1); }
    block_bar();
    lgkm0();
    spin();
    __builtin_amdgcn_s_setprio(1);
#pragma unroll
    for (int j = 0; j < 4; ++j)
#pragma unroll
      for (int i = 0; i < 4; ++i)
        acc[i][j] = mfma8(af[i], bfr[j], acc[i][j]);
    __builtin_amdgcn_s_setprio(0);
    spin();
    block_bar();
    f16x8 af2[4];
#pragma unroll
    for (int i = 0; i < 4; ++i)
      af2[i] = *(const f16x8*)&sAb[cur * 8192 + (wm + 64 + i * 16 + l16) * 32 + cread];
    if (st) { stageB(b2, t + 2, 0); stageB(b2, t + 2, 1); }
    block_bar();
    lgkm0();
    spin();
    __builtin_amdgcn_s_setprio(1);
#pragma unroll
    for (int j = 0; j < 4; ++j)
#pragma unroll
      for (int i = 0; i < 4; ++i)
        acc[4 + i][j] = mfma8(af2[i], bfr[j], acc[4 + i][j]);
    __builtin_amdgcn_s_setprio(0);
    spin();
    if (t + 1 < NT) {
      if (st) vwait<LPT>(); else vwait<0>();
      block_bar();
    }
  };

  for (int p = 0; p < NT / 3; ++p) {   // static buffer indices (x3 unroll)
    const int t = p * 3;
    tile_step(t + 0, 0, 2);
    tile_step(t + 1, 1, 0);
    tile_step(t + 2, 2, 1);
  }

  // ---- fp32 raw-score store: round-3 VERIFIED path (issued first so the
  // vmem stores fly under the stats phase below) ----
  float* C = Sc + (long)z * 4194304;   // batch pitch 2048*2048
#pragma unroll
  for (int i = 0; i < 8; ++i) {
    const int mb = bm + wm + i * 16 + quad * 4;
#pragma unroll
    for (int j = 0; j < 4; ++j) {
      const int n = bn + wn + j * 16 + l16;
#pragma unroll
      for (int r = 0; r < 4; ++r)
        C[(long)(mb + r) * 2048 + n] = acc[i][j][r];
    }
  }

  // ---- tile stats (round-4/8 verified math; acc preserved) ----
  block_bar();
  float* red = (float*)smem;           // [256][4] max ; sums at +1024 floats
  const int wnid = wave & 3;
  float m_[8][4];
  {
    float mx_[8][4];
#pragma unroll
    for (int i = 0; i < 8; ++i)
#pragma unroll
      for (int r = 0; r < 4; ++r) {
        float v = fmaxf(fmaxf(acc[i][0][r], acc[i][1][r]),
                        fmaxf(acc[i][2][r], acc[i][3][r]));
#pragma unroll
        for (int o = 8; o >= 1; o >>= 1) v = fmaxf(v, __shfl_xor(v, o));
        mx_[i][r] = v;
      }
    if (l16 == 0) {
#pragma unroll
      for (int i = 0; i < 8; ++i)
#pragma unroll
        for (int r = 0; r < 4; ++r)
          red[(wm + i * 16 + quad * 4 + r) * 4 + wnid] = mx_[i][r];
    }
  }
  lgkm0();
  block_bar();
#pragma unroll
  for (int i = 0; i < 8; ++i)
#pragma unroll
    for (int r = 0; r < 4; ++r) {
      const f32x4 v = *(const f32x4*)&red[(wm + i * 16 + quad * 4 + r) * 4];
      m_[i][r] = fmaxf(fmaxf(v[0], v[1]), fmaxf(v[2], v[3]));
    }
  {
    float sm_[8][4];
#pragma unroll
    for (int i = 0; i < 8; ++i)
#pragma unroll
      for (int r = 0; r < 4; ++r) {
        float ssum = 0.f;
#pragma unroll
        for (int j = 0; j < 4; ++j)
          ssum += exp2f((acc[i][j][r] - m_[i][r]) * LOG2E);
#pragma unroll
        for (int o = 8; o >= 1; o >>= 1) ssum += __shfl_xor(ssum, o);
        sm_[i][r] = ssum;
      }
    lgkm0();
    block_bar();   // everyone done reading max region before sums overwrite? (disjoint region, but keep convergent order)
    if (l16 == 0) {
#pragma unroll
      for (int i = 0; i < 8; ++i)
#pragma unroll
        for (int r = 0; r < 4; ++r)
          red[1024 + (wm + i * 16 + quad * 4 + r) * 4 + wnid] = sm_[i][r];
    }
  }
  lgkm0();
  block_bar();
  if (wnid == 0 && l16 == 0) {
    float* mxo = mxg + ((long)z * 8 + bxi) * 2048 + bm;
    float* smo = smg + ((long)z * 8 + bxi) * 2048 + bm;
#pragma unroll
    for (int i = 0; i < 8; ++i)
#pragma unroll
      for (int r = 0; r < 4; ++r) {
        const int row = wm + i * 16 + quad * 4 + r;
        const f32x4 v = *(const f32x4*)&red[1024 + row * 4];
        mxo[row] = m_[i][r];
        smo[row] = (v[0] + v[1]) + (v[2] + v[3]);
      }
  }
}

// Per-row global norm constants: nrm[R][0] = -M*log2e, nrm[R][1] = 1/(S*sqrt768)
// so p = exp2(fma(s, LOG2E, nrm0)) * nrm1 is the exact reference softmax/sqrt(d).
__global__ __launch_bounds__(256)
void combine(const float* __restrict__ mxg, const float* __restrict__ smg,
             float* __restrict__ nrm) {
  const int R = blockIdx.x * 256 + threadIdx.x;   // 0..16383 = z*2048+m
  const int z = R >> 11, m = R & 2047;
  float mx[8], sm[8];
#pragma unroll
  for (int t = 0; t < 8; ++t) {
    mx[t] = mxg[((long)z * 8 + t) * 2048 + m];
    sm[t] = smg[((long)z * 8 + t) * 2048 + m];
  }
  float M = mx[0];
#pragma unroll
  for (int t = 1; t < 8; ++t) M = fmaxf(M, mx[t]);
  float S = 0.f;
#pragma unroll
  for (int t = 0; t < 8; ++t) S += sm[t] * exp2f((mx[t] - M) * LOG2E);
  float2 o;
  o.x = -M * LOG2E;
  o.y = 1.0f / (S * SQRT_E);
  *(float2*)&nrm[(long)R * 2] = o;
}

// ---------------------------------------------------------------------------
// PV with fused normalize: O = P * vT^T where P = exp2(s*log2e + nrm0)*nrm1,
// computed at STAGE time from raw fp32 scores. A-side is reg-staged (plain
// fp32 loads -> exp/cvt -> ds_write_b128 to the SAME linear LDS bytes the
// gload_lds path used, so the verified cs0 read-swizzle is unchanged).
// B-side (V) keeps verified gload_lds. Simple sync 2-buffer pipeline:
//   issue loads(t+1) ; compute(t) ; vwait0 ; cvt+ds_write(t+1) ; lgkm0 ; bar
// Compute/epilogue identical to round-4's verified pv_pipe.
// ---------------------------------------------------------------------------
__global__ __launch_bounds__(256, 2)
void pv_norm(const float* __restrict__ Sc, const f16* __restrict__ Vt,
             const float* __restrict__ nrm, float* __restrict__ out) {
  __shared__ __align__(16) f16 sA[2][128 * 64];
  __shared__ __align__(16) f16 sB[2][128 * 64];

  const int id = blockIdx.x;
  const int xcd = id & 7;
  const int j0 = id >> 3;
  const int s = j0 / 6;
  const int bxi = j0 - s * 6;
  const int g = xcd + 8 * s;   // 0..127
  const int byi = g & 15;
  const int z = g >> 4;

  const float* pA = Sc + (long)z * 4194304;
  const f16* pB = Vt + (long)z * 1572864;

  const int bm = byi * 128;
  const int bn = bxi * 128;
  const int tid = threadIdx.x;
  const int wave = tid >> 6;
  const int lane = tid & 63;
  const int wm = (wave >> 1) * 64;
  const int wn = (wave & 1) * 64;
  const int quad = lane >> 4;
  const int l16 = lane & 15;

  f32x4 acc[4][4] = {};

  const int srow = tid >> 3;           // 0..31
  const int schk = tid & 7;
  const int swc = (schk ^ (srow & 7)) * 8;   // swizzled 8-elem chunk offset
  const int cs0 = (quad * 8) ^ ((l16 & 7) << 3);

  // per-row norm constants for the 4 rows this thread stages
  float nmx[4], ninv[4];
#pragma unroll
  for (int l = 0; l < 4; ++l) {
    const int r = bm + l * 32 + srow;
    const float2 mv = *(const float2*)&nrm[((long)z * 2048 + r) * 2];
    nmx[l] = mv.x; ninv[l] = mv.y;
  }

  float4 ra[4][2];
  auto issueA = [&](int t) {
    const long co = (long)t * 64 + swc;
#pragma unroll
    for (int l = 0; l < 4; ++l) {
      const float* p = pA + (long)(bm + l * 32 + srow) * 2048 + co;
      ra[l][0] = *(const float4*)p;
      ra[l][1] = *(const float4*)(p + 4);
    }
  };
  auto stageB = [&](int buf, int t) {
    const long ka = (long)t * 64 + swc;
#pragma unroll
    for (int l = 0; l < 4; ++l)
      async16(pB + (long)(bn + l * 32 + srow) * 2048 + ka,
              &sB[buf][(l * 256 + tid) * 8]);
  };
  auto writeA = [&](int buf) {
#pragma unroll
    for (int l = 0; l < 4; ++l) {
      union { f16 h[8]; uint4 u; } P;
      const float* a0 = (const float*)&ra[l][0];
      const float* a1 = (const float*)&ra[l][1];
#pragma unroll
      for (int e = 0; e < 4; ++e) {
        P.h[e]     = (f16)(exp2f(fmaf(a0[e], LOG2E, nmx[l])) * ninv[l]);
        P.h[e + 4] = (f16)(exp2f(fmaf(a1[e], LOG2E, nmx[l])) * ninv[l]);
      }
      *(uint4*)&sA[buf][(l * 256 + tid) * 8] = P.u;
    }
  };

  auto compute = [&](int buf) {
    f16x8 bf[2][4];
#pragma unroll
    for (int kk = 0; kk < 2; ++kk)
#pragma unroll
      for (int jj = 0; jj < 4; ++jj)
        bf[kk][jj] = *(const f16x8*)&sB[buf][(wn + jj * 16 + l16) * 64 +
                                            (cs0 ^ (kk * 32))];
#pragma unroll
    for (int mq = 0; mq < 2; ++mq) {
      f16x8 af[2][2];
#pragma unroll
      for (int kk = 0; kk < 2; ++kk)
#pragma unroll
        for (int ii = 0; ii < 2; ++ii)
          af[kk][ii] =
              *(const f16x8*)&sA[buf][(wm + mq * 32 + ii * 16 + l16) * 64 +
                                      (cs0 ^ (kk * 32))];
      __builtin_amdgcn_s_setprio(1);
#pragma unroll
      for (int jj = 0; jj < 4; ++jj)
#pragma unroll
        for (int ii = 0; ii < 2; ++ii)
#pragma unroll
          for (int kk = 0; kk < 2; ++kk)
            acc[mq * 2 + ii][jj] =
                mfma8(af[kk][ii], bf[kk][jj], acc[mq * 2 + ii][jj]);
      __builtin_amdgcn_s_setprio(0);
    }
  };

  // prologue: tile 0
  issueA(0);
  stageB(0, 0);
  vwait<0>();
  writeA(0);
  lgkm0();
  block_bar();

  constexpr int NT = 32;
  int cur = 0;
  for (int t = 0; t < NT; ++t) {
    if (t + 1 < NT) { issueA(t + 1); stageB(cur ^ 1, t + 1); }
    spin();
    compute(cur);
    if (t + 1 < NT) {
      vwait<0>();
      writeA(cur ^ 1);
      lgkm0();
      block_bar();
      cur ^= 1;
    }
  }

  float* C = out + (long)z * 1572864;
#pragma unroll
  for (int i = 0; i < 4; ++i) {
    const int mb = bm + wm + i * 16 + quad * 4;
#pragma unroll
    for (int j = 0; j < 4; ++j) {
      const int n = bn + wn + j * 16 + l16;
#pragma unroll
      for (int r = 0; r < 4; ++r)
        C[(long)(mb + r) * 768 + n] = acc[i][j][r];
    }
  }
}

// ---------------------------------------------------------------------------
// 2-phase pipelined GEMM (round-2 verified) — y and v projections.
// ---------------------------------------------------------------------------
template <typename T, typename TO, int BMt, int BNt, int BKt, int AT, int EPI>
__global__ __launch_bounds__((BMt == 256 ? 512 : 256), 2)
void gemm_pipe(const T* __restrict__ Ah, const T* __restrict__ Al,
               const T* __restrict__ Bh, void* __restrict__ C0,
               int K, long lda, long ldb, long ldc,
               long stA, long stB, long stC, int gxN, int gyM) {
  using vec8 = typename std::conditional<std::is_same<T, bf16>::value,
                                         bf16x8, f16x8>::type;
  static_assert(BMt == BNt, "square tiles only");
  constexpr int THREADS = (BMt == 256) ? 512 : 256;
  constexpr int NWN = (BMt == 256) ? 4 : 2;
  constexpr int WTM = BMt / 2;
  constexpr int WTN = BNt / NWN;
  static_assert(WTN == 64, "wave tile must be 64 wide");
  constexpr int MF = WTM / 16;
  constexpr int KK = BKt / 32;
  constexpr int CPR = BKt / 8;
  constexpr int RPI = THREADS / CPR;
  constexpr int LPP = (BMt * BKt) / (THREADS * 8);
  constexpr int LPT = LPP * (AT == 2 ? 3 : 2);

  __shared__ __align__(16) T sA[2][BMt * BKt];
  __shared__ __align__(16) T sB[2][BNt * BKt];
  __shared__ __align__(16) T sAl[AT == 2 ? 2 * BMt * BKt : 8];

  const int id = blockIdx.x;
  const int xcd = id & 7;
  const int j0 = id >> 3;
  const int s = j0 / gxN;
  const int bxi = j0 - s * gxN;
  const int g = xcd + 8 * s;
  const int byi = g % gyM;
  const int z = g / gyM;

  const T* pA = Ah + (long)z * stA;
  const T* pB = Bh + (long)z * stB;
  const T* pAl = (AT == 2) ? Al : nullptr;

  const int bm = byi * BMt;
  const int bn = bxi * BNt;
  const int tid = threadIdx.x;
  const int wave = tid >> 6;
  const int lane = tid & 63;
  const int wm = (wave / NWN) * WTM;
  const int wn = (wave % NWN) * WTN;
  const int quad = lane >> 4;
  const int l16 = lane & 15;

  f32x4 acc[MF][4] = {};

  const int srow = tid / CPR;
  const int schk = tid % CPR;
  const int swc = ((BKt == 64) ? (schk ^ (srow & 7)) : schk) * 8;
  const int cs0 = (quad * 8) ^ ((BKt == 64) ? ((l16 & 7) << 3) : 0);

  const int NT = K / BKt;

  auto stage = [&](int buf, int t) {
    const long ka = (long)t * BKt + swc;
#pragma unroll
    for (int l = 0; l < LPP; ++l)
      async16(pA + (long)(bm + l * RPI + srow) * lda + ka,
              &sA[buf][(l * THREADS + tid) * 8]);
#pragma unroll
    for (int l = 0; l < LPP; ++l)
      async16(pB + (long)(bn + l * RPI + srow) * ldb + ka,
              &sB[buf][(l * THREADS + tid) * 8]);
    if constexpr (AT == 2) {
#pragma unroll
      for (int l = 0; l < LPP; ++l)
        async16(pAl + (long)(bm + l * RPI + srow) * lda + ka,
                &sAl[buf * BMt * BKt + (l * THREADS + tid) * 8]);
    }
  };

  auto compute = [&](int buf) {
    const T* bA = &sA[buf][0];
    const T* bB = &sB[buf][0];
    const T* bAl = (AT == 2) ? &sAl[buf * BMt * BKt] : nullptr;
    vec8 bf[KK][4];
#pragma unroll
    for (int kk = 0; kk < KK; ++kk)
#pragma unroll
      for (int jj = 0; jj < 4; ++jj)
        bf[kk][jj] =
            *(const vec8*)&bB[(wn + jj * 16 + l16) * BKt + (cs0 ^ (kk * 32))];
#pragma unroll
    for (int mq = 0; mq < MF / 2; ++mq) {
      vec8 af[KK][2];
      vec8 alf[AT == 2 ? KK : 1][2];
#pragma unroll
      for (int kk = 0; kk < KK; ++kk)
#pragma unroll
        for (int ii = 0; ii < 2; ++ii) {
          const int r = wm + mq * 32 + ii * 16 + l16;
          af[kk][ii] = *(const vec8*)&bA[r * BKt + (cs0 ^ (kk * 32))];
          if constexpr (AT == 2)
            alf[kk][ii] = *(const vec8*)&bAl[r * BKt + (cs0 ^ (kk * 32))];
        }
      __builtin_amdgcn_s_setprio(1);
#pragma unroll
      for (int jj = 0; jj < 4; ++jj)
#pragma unroll
        for (int ii = 0; ii < 2; ++ii)
#pragma unroll
          for (int kk = 0; kk < KK; ++kk) {
            acc[mq * 2 + ii][jj] =
                mfma8(af[kk][ii], bf[kk][jj], acc[mq * 2 + ii][jj]);
            if constexpr (AT == 2)
              acc[mq * 2 + ii][jj] =
                  mfma8(alf[kk][ii], bf[kk][jj], acc[mq * 2 + ii][jj]);
          }
      __builtin_amdgcn_s_setprio(0);
    }
  };

  stage(0, 0);
  stage(1, 1);
  vwait<LPT>();
  block_bar();

  for (int t = 0; t < NT; ++t) {
    const int cur = t & 1;
    compute(cur);
    if (t + 1 < NT) {
      block_bar();
      if (t + 2 < NT) {
        stage(cur, t + 2);
        vwait<LPT>();
      } else {
        vwait<0>();
      }
      block_bar();
    }
  }

  if constexpr (EPI == EPI_F16) {
    TO* Ch = (TO*)C0;
#pragma unroll
    for (int i = 0; i < MF; ++i) {
      const int mb = bm + wm + i * 16 + quad * 4;
#pragma unroll
      for (int j = 0; j < 4; ++j) {
        const int n = bn + wn + j * 16 + l16;
#pragma unroll
        for (int r = 0; r < 4; ++r)
          Ch[(long)(mb + r) * ldc + n] = (TO)acc[i][j][r];
      }
    }
  } else if constexpr (EPI == EPI_VT) {
    TO* vT = (TO*)C0;
#pragma unroll
    for (int i = 0; i < MF; ++i) {
      const int mb = bm + wm + i * 16 + quad * 4;
      const long bb = mb >> 11;
      const long ml = mb & 2047;
#pragma unroll
      for (int j = 0; j < 4; ++j) {
        const int e = bn + wn + j * 16 + l16;
        union { TO b[4]; uint2 u; } P;
#pragma unroll
        for (int r = 0; r < 4; ++r) P.b[r] = (TO)acc[i][j][r];
        *(uint2*)&vT[(bb * 768 + e) * 2048 + ml] = P.u;
      }
    }
  } else {  // EPI_F32
    float* C = (float*)C0 + (long)z * stC;
#pragma unroll
    for (int i = 0; i < MF; ++i) {
      const int mb = bm + wm + i * 16 + quad * 4;
#pragma unroll
      for (int j = 0; j < 4; ++j) {
        const int n = bn + wn + j * 16 + l16;
#pragma unroll
        for (int r = 0; r < 4; ++r)
          C[(long)(mb + r) * ldc + n] = acc[i][j][r];
      }
    }
  }
}

// ---------------------------------------------------------------------------
// Old 128x128/BK64 drain kernel (verified) — kept for the small Mt GEMM only.
// ---------------------------------------------------------------------------
constexpr int BM = 128, BN = 128, BK = 64;

template <typename T, typename TO, int AT, int BT, int EPI, int SWZ>
__global__ __launch_bounds__(256)
void gemm_kernel(const T* __restrict__ Ah, const T* __restrict__ Al,
                 const T* __restrict__ Bh, const T* __restrict__ Bl,
                 void* __restrict__ C0, void* __restrict__ C1,
                 int K, long lda, long ldb, long ldbl, long ldc,
                 long stA, long stB, long stBl, long stC,
                 int gxN, int gyM) {
  using vec8 = typename std::conditional<std::is_same<T, bf16>::value,
                                         bf16x8, f16x8>::type;
  __shared__ __align__(16) T sAh[BM * BK];
  __shared__ __align__(16) T sBh[BN * BK];
  __shared__ __align__(16) T sAl[AT == 2 ? BM * BK : 8];
  __shared__ __align__(16) T sBl[BT == 2 ? BN * BK : 8];

  int bxi, byi, z;
  if constexpr (SWZ) {
    const int id = blockIdx.x;
    const int xcd = id & 7;
    const int j = id >> 3;
    const int s = j / gxN;
    const int n = j - s * gxN;
    const int g = xcd + 8 * s;
    bxi = n;
    byi = g % gyM;
    z = g / gyM;
  } else {
    bxi = blockIdx.x; byi = blockIdx.y; z = blockIdx.z;
  }

  const T* pAh = Ah + (long)z * stA;
  const T* pBh = Bh + (long)z * stB;
  const T* pAl = (AT == 2) ? (Al + (long)z * stA) : nullptr;
  const T* pBl = (BT == 2) ? (Bl + (long)z * stBl) : nullptr;

  const int bm = byi * BM;
  const int bn = bxi * BN;
  const int tid = threadIdx.x;
  const int wave = tid >> 6;
  const int lane = tid & 63;
  const int wm = (wave & 1) * 64;
  const int wn = (wave >> 1) * 64;
  const int quad = lane >> 4;
  const int l16 = lane & 15;

  f32x4 acc[4][4] = {};

  const int sr0 = tid >> 3;
  const int swc = ((tid & 7) ^ (sr0 & 7)) * 8;
  const int cs0 = (quad * 8) ^ ((l16 & 7) << 3);

  for (int kt = 0; kt < K; kt += BK) {
    __syncthreads();
    {
      const long ka = kt + swc;
#pragma unroll
      for (int l = 0; l < 4; ++l) {
        const int row = l * 32 + sr0;
        async16(pAh + (long)(bm + row) * lda + ka, &sAh[(l * 256 + tid) * 8]);
      }
#pragma unroll
      for (int l = 0; l < 4; ++l) {
        const int row = l * 32 + sr0;
        async16(pBh + (long)(bn + row) * ldb + ka, &sBh[(l * 256 + tid) * 8]);
      }
      if constexpr (AT == 2) {
#pragma unroll
        for (int l = 0; l < 4; ++l) {
          const int row = l * 32 + sr0;
          async16(pAl + (long)(bm + row) * lda + ka, &sAl[(l * 256 + tid) * 8]);
        }
      }
      if constexpr (BT == 2) {
#pragma unroll
        for (int l = 0; l < 4; ++l) {
          const int row = l * 32 + sr0;
          async16(pBl + (long)(bn + row) * ldbl + ka, &sBl[(l * 256 + tid) * 8]);
        }
      }
    }
    __syncthreads();

#pragma unroll
    for (int kk = 0; kk < 2; ++kk) {
      const int cs = cs0 ^ (kk * 32);
      vec8 ah[4], al[4];
#pragma unroll
      for (int i = 0; i < 4; ++i) {
        ah[i] = *(const vec8*)&sAh[(wm + i * 16 + l16) * BK + cs];
        if constexpr (AT == 2)
          al[i] = *(const vec8*)&sAl[(wm + i * 16 + l16) * BK + cs];
      }
#pragma unroll
      for (int j = 0; j < 4; ++j) {
        const vec8 bh = *(const vec8*)&sBh[(wn + j * 16 + l16) * BK + cs];
        vec8 bl;
        if constexpr (BT == 2)
          bl = *(const vec8*)&sBl[(wn + j * 16 + l16) * BK + cs];
#pragma unroll
        for (int i = 0; i < 4; ++i) {
          acc[i][j] = mfma8(ah[i], bh, acc[i][j]);
          if constexpr (BT == 2) acc[i][j] = mfma8(ah[i], bl, acc[i][j]);
          if constexpr (AT == 2) acc[i][j] = mfma8(al[i], bh, acc[i][j]);
        }
      }
    }
  }

  if constexpr (EPI == EPI_PAIR) {
    TO* Ch = (TO*)C0;
    TO* Cl = (TO*)C1;
#pragma unroll
    for (int i = 0; i < 4; ++i) {
      const int mb = bm + wm + i * 16 + quad * 4;
#pragma unroll
      for (int j = 0; j < 4; ++j) {
        const int n = bn + wn + j * 16 + l16;
#pragma unroll
        for (int r = 0; r < 4; ++r) {
          const float f = acc[i][j][r];
          const TO h = (TO)f;
          const long idx = (long)(mb + r) * ldc + n;
          Ch[idx] = h;
          Cl[idx] = (TO)(f - (float)h);
        }
      }
    }
  }
}

// Fused fp32 -> f16: x -> hi/lo pair; Wv -> single.
__global__ __launch_bounds__(256)
void split_all(const float4* __restrict__ x, const float4* __restrict__ wv,
               uint2* __restrict__ xh, uint2* __restrict__ xl,
               uint2* __restrict__ wvh) {
  constexpr int NX = 3145728;
  constexpr int NWV = 147456;
  const int i = blockIdx.x * 256 + threadIdx.x;
  float4 v;
  uint2 *dh, *dl;
  if (i < NX) {
    v = x[i]; dh = xh + i; dl = xl + i;
  } else {
    const int m = i - NX;
    if (m >= NWV) return;
    v = wv[m]; dh = wvh + m; dl = nullptr;
  }
  const f16 h0 = (f16)v.x, h1 = (f16)v.y, h2 = (f16)v.z, h3 = (f16)v.w;
  union { f16 b[4]; uint2 u; } P;
  P.b[0] = h0; P.b[1] = h1; P.b[2] = h2; P.b[3] = h3;
  *dh = P.u;
  if (dl != nullptr) {
    P.b[0] = (f16)(v.x - (float)h0);
    P.b[1] = (f16)(v.y - (float)h1);
    P.b[2] = (f16)(v.z - (float)h2);
    P.b[3] = (f16)(v.w - (float)h3);
    *dl = P.u;
  }
}

// Transpose 768x768 fp32 W[e][d] -> f16 hi/lo pair WT[d][e] (e contiguous).
__global__ __launch_bounds__(256)
void transpose_split(const float* __restrict__ Wq, const float* __restrict__ Wk,
                     f16* __restrict__ qTh, f16* __restrict__ qTl,
                     f16* __restrict__ kTh, f16* __restrict__ kTl) {
  __shared__ float tile[64][65];
  const float* src = blockIdx.z ? Wk : Wq;
  f16* dh = blockIdx.z ? kTh : qTh;
  f16* dl = blockIdx.z ? kTl : qTl;
  const int e0 = blockIdx.y * 64, d0 = blockIdx.x * 64;
  const int t = threadIdx.x;
  const int r = t >> 2;
  const int c4 = (t & 3) * 16;
  const float4* s4 = (const float4*)(src + (long)(e0 + r) * 768 + d0 + c4);
#pragma unroll
  for (int g = 0; g < 4; ++g) {
    const float4 v = s4[g];
    tile[r][c4 + g * 4 + 0] = v.x;
    tile[r][c4 + g * 4 + 1] = v.y;
    tile[r][c4 + g * 4 + 2] = v.z;
    tile[r][c4 + g * 4 + 3] = v.w;
  }
  __syncthreads();
  union { f16 b[8]; uint4 u; } H0, H1, L0, L1;
#pragma unroll
  for (int i = 0; i < 16; ++i) {
    const float v = tile[c4 + i][r];
    const f16 h = (f16)v;
    const f16 l = (f16)(v - (float)h);
    if (i < 8) { H0.b[i] = h; L0.b[i] = l; }
    else       { H1.b[i - 8] = h; L1.b[i - 8] = l; }
  }
  const long o = (long)(d0 + r) * 768 + e0 + c4;
  *(uint4*)(dh + o) = H0.u;  *(uint4*)(dh + o + 8) = H1.u;
  *(uint4*)(dl + o) = L0.u;  *(uint4*)(dl + o + 8) = L1.u;
}

extern "C" void kernel_launch(void* const* d_in, const int* in_sizes, int n_in,
                              void* d_out, int out_size, void* d_ws, size_t ws_size,
                              hipStream_t stream) {
  const float* x  = (const float*)d_in[0];
  const float* Wq = (const float*)d_in[1];
  const float* Wk = (const float*)d_in[2];
  const float* Wv = (const float*)d_in[3];
  float* out = (float*)d_out;
  char* ws = (char*)d_ws;

  // ---- workspace layout (bytes) ----
  const size_t SZ = 25165824;      // 16384*768*2
  f16* yh = (f16*)(ws + 0 * SZ);
  // yl slot [SZ, 2SZ) is dead since round 1 -> host stats + nrm there (4.3 MB)
  float* mxg = (float*)(ws + SZ);                 // [8][8][2048] = 2 MB
  float* smg = (float*)(ws + SZ + 2097152);       // 2 MB
  float* nrm = (float*)(ws + SZ + 4194304);       // [16384][2] = 128 KB
  f16* xh = (f16*)(ws + 2 * SZ);
  f16* vT = (f16*)(ws + 3 * SZ);
  const size_t PERS = 4 * SZ;      // 100663296
  const size_t WT = 1179648;       // 768*768 f16
  f16* xl   = (f16*)(ws + PERS);
  f16* wqTh = (f16*)(ws + PERS + SZ);
  f16* wqTl = (f16*)(ws + PERS + SZ + 1 * WT);
  f16* wkTh = (f16*)(ws + PERS + SZ + 2 * WT);
  f16* wkTl = (f16*)(ws + PERS + SZ + 3 * WT);
  f16* mtH  = (f16*)(ws + PERS + SZ + 4 * WT);
  f16* mtL  = (f16*)(ws + PERS + SZ + 5 * WT);
  f16* wvh  = (f16*)(ws + PERS + SZ + 6 * WT);
  float* scores = (float*)(ws + PERS);            // [8][2048][2048] fp32

  // ---- phase 1 ----
  split_all<<<12864, 256, 0, stream>>>(
      (const float4*)x, (const float4*)Wv, (uint2*)xh, (uint2*)xl, (uint2*)wvh);
  transpose_split<<<dim3(12, 12, 2), 256, 0, stream>>>(
      Wq, Wk, wqTh, wqTl, wkTh, wkTl);

  // M^T[d'][d] = sum_e WkT[d'][e] * WqT[d][e]  (3-term, f16 pair out)
  gemm_kernel<f16, f16, 2, 2, EPI_PAIR, 0><<<dim3(6, 6, 1), 256, 0, stream>>>(
      wkTh, wkTl, wqTh, wqTl, (void*)mtH, (void*)mtL,
      768, 768, 768, 768, 768, 0, 0, 0, 0, 0, 0);

  // y = (xh+xl) * MT_h^T : f16 hi only, 2-term, BK32 dbuf
  gemm_pipe<f16, f16, 128, 128, 32, 2, EPI_F16><<<768, 256, 0, stream>>>(
      xh, xl, mtH, (void*)yh, 768, 768, 768, 768, 0, 0, 0, 6, 128);

  // v = xh * Wv_h^T -> vT f16 transposed, 1-term, BK64 dbuf
  gemm_pipe<f16, f16, 128, 128, 64, 1, EPI_VT><<<768, 256, 0, stream>>>(
      xh, nullptr, wvh, (void*)vT, 768, 768, 768, 0, 0, 0, 0, 6, 128);

  // ---- phase 2: S(fp32 + stats) -> combine -> PV(fused normalize) ----
  s_ring<<<512, 512, 0, stream>>>(yh, xh, scores, mxg, smg);
  combine<<<64, 256, 0, stream>>>(mxg, smg, nrm);
  pv_norm<<<768, 256, 0, stream>>>(scores, vT, nrm, out);
}

// Round 11
// 381.534 us; speedup vs baseline: 1.1130x; 1.1130x over previous
//
#include <hip/hip_runtime.h>
#include <stdint.h>
#include <type_traits>

typedef __bf16 bf16;
typedef _Float16 f16;
typedef bf16 bf16x8 __attribute__((ext_vector_type(8)));
typedef f16 f16x8 __attribute__((ext_vector_type(8)));
typedef float f32x4 __attribute__((ext_vector_type(4)));

#define LOG2E 1.4426950408889634f
#define SQRT_E 27.712812921102035f

enum { EPI_F32 = 0, EPI_PAIR = 1, EPI_VT = 2, EPI_F16 = 3 };

__device__ __forceinline__ void async16(const void* g, void* l) {
  __builtin_amdgcn_global_load_lds(
      (__attribute__((address_space(1))) void*)(uintptr_t)g,
      (__attribute__((address_space(3))) void*)l, 16, 0, 0);
}

__device__ __forceinline__ f32x4 mfma8(bf16x8 a, bf16x8 b, f32x4 c) {
  return __builtin_amdgcn_mfma_f32_16x16x32_bf16(a, b, c, 0, 0, 0);
}
__device__ __forceinline__ f32x4 mfma8(f16x8 a, f16x8 b, f32x4 c) {
  return __builtin_amdgcn_mfma_f32_16x16x32_f16(a, b, c, 0, 0, 0);
}

template <int N>
__device__ __forceinline__ void vwait() {
  asm volatile("s_waitcnt vmcnt(%0)" ::"i"(N) : "memory");
}
__device__ __forceinline__ void block_bar() {
  asm volatile("" ::: "memory");
  __builtin_amdgcn_s_barrier();
  asm volatile("" ::: "memory");
}
__device__ __forceinline__ void lgkm0() {
  asm volatile("s_waitcnt lgkmcnt(0)" ::: "memory");
}
__device__ __forceinline__ void spin() { __builtin_amdgcn_sched_barrier(0); }

// ---------------------------------------------------------------------------
// Fine-phase ring GEMM (round-3 verified schedule): C[M,N] = A[M,K]*B[N,K]^T.
// 256x256 tile, BK=32, 512 threads (8 waves 2Mx4N, wave tile 128x64),
// 3-buffer LDS ring. Per tile t: two phases, each {ds_read frags; stage 2
// loads of t+2; BAR; lgkm0; setprio; 16 MFMA; setprio; BAR}; counted
// vwait<LPT> at tile end (t+2's loads stay in flight). Race-freedom per
// round-2/3 analysis. BK=32 chunk-XOR swizzle both sides (0 conflicts,
// HW-verified). z-major decode (nz>0): one batch per XCD (FETCH 110->37 MB,
// HW-verified).
// UNR=1: K-loop statically unrolled x3 (NT%3==0 required) so buffer indices
// are compile-time constants (m201's static-dbuf property; removes runtime
// modular indexing from every LDS address chain).
// ---------------------------------------------------------------------------
template <typename T, typename TO, int AT, int EPI, int UNR>
__global__ __launch_bounds__(512, 2)
void gemm_ring(const T* __restrict__ Ah, const T* __restrict__ Al,
               const T* __restrict__ Bh, void* __restrict__ C0,
               int K, long lda, long ldb, long ldc,
               long stA, long stB, long stC, int gxN, int gyM, int nz) {
  using vec8 = typename std::conditional<std::is_same<T, bf16>::value,
                                         bf16x8, f16x8>::type;
  constexpr int LPT = (AT == 2) ? 6 : 4;
  __shared__ __align__(16) T sA[3][256 * 32];
  __shared__ __align__(16) T sB[3][256 * 32];
  __shared__ __align__(16) T sAl[AT == 2 ? 3 * 256 * 32 : 8];

  const int id = blockIdx.x;
  const int xcd = id & 7;
  const int j0 = id >> 3;
  const int s = j0 / gxN;
  const int bxi = j0 - s * gxN;
  const int g = xcd + 8 * s;
  int byi, z;
  if (nz > 0) { z = g % nz; byi = g / nz; }
  else        { byi = g % gyM; z = g / gyM; }

  const T* pA = Ah + (long)z * stA;
  const T* pB = Bh + (long)z * stB;
  const T* pAl = (AT == 2) ? Al : nullptr;

  const int bm = byi * 256;
  const int bn = bxi * 256;
  const int tid = threadIdx.x;
  const int wave = tid >> 6;
  const int lane = tid & 63;
  const int wm = (wave >> 2) * 128;
  const int wn = (wave & 3) * 64;
  const int quad = lane >> 4;
  const int l16 = lane & 15;

  f32x4 acc[8][4] = {};

  const int srow = tid >> 2;
  const int swc = ((tid & 3) ^ ((tid >> 3) & 3)) * 8;
  const int cread = (quad ^ ((l16 >> 1) & 3)) * 8;

  const int NT = K / 32;

  auto stageA = [&](int buf, int t, int l) {
    const long ka = (long)t * 32 + swc;
    async16(pA + (long)(bm + l * 128 + srow) * lda + ka,
            &sA[buf][(l * 512 + tid) * 8]);
  };
  auto stageB = [&](int buf, int t, int l) {
    const long ka = (long)t * 32 + swc;
    async16(pB + (long)(bn + l * 128 + srow) * ldb + ka,
            &sB[buf][(l * 512 + tid) * 8]);
  };
  auto stageAl = [&](int buf, int t, int l) {
    const long ka = (long)t * 32 + swc;
    async16(pAl + (long)(bm + l * 128 + srow) * lda + ka,
            &sAl[buf * 8192 + (l * 512 + tid) * 8]);
  };

  stageA(0, 0, 0); stageA(0, 0, 1); stageB(0, 0, 0); stageB(0, 0, 1);
  if constexpr (AT == 2) { stageAl(0, 0, 0); stageAl(0, 0, 1); }
  stageA(1, 1, 0); stageA(1, 1, 1); stageB(1, 1, 0); stageB(1, 1, 1);
  if constexpr (AT == 2) { stageAl(1, 1, 0); stageAl(1, 1, 1); }
  vwait<LPT>();
  block_bar();

  // One K-tile: phases 0/1 exactly as verified in round 3. cur/b2 become
  // compile-time constants under UNR=1 inlining.
  auto tile_step = [&](int t, int cur, int b2) {
    const bool st = (t + 2 < NT);
    vec8 bfr[4], af[4], alf[AT == 2 ? 4 : 1];
#pragma unroll
    for (int j = 0; j < 4; ++j)
      bfr[j] = *(const vec8*)&sB[cur][(wn + j * 16 + l16) * 32 + cread];
#pragma unroll
    for (int i = 0; i < 4; ++i) {
      af[i] = *(const vec8*)&sA[cur][(wm + i * 16 + l16) * 32 + cread];
      if constexpr (AT == 2)
        alf[i] = *(const vec8*)&sAl[cur * 8192 + (wm + i * 16 + l16) * 32 + cread];
    }
    if (st) {
      stageA(b2, t + 2, 0); stageA(b2, t + 2, 1);
      if constexpr (AT == 2) stageAl(b2, t + 2, 0);
    }
    block_bar();
    lgkm0();
    spin();
    __builtin_amdgcn_s_setprio(1);
#pragma unroll
    for (int j = 0; j < 4; ++j)
#pragma unroll
      for (int i = 0; i < 4; ++i) {
        acc[i][j] = mfma8(af[i], bfr[j], acc[i][j]);
        if constexpr (AT == 2) acc[i][j] = mfma8(alf[i], bfr[j], acc[i][j]);
      }
    __builtin_amdgcn_s_setprio(0);
    spin();
    block_bar();
    vec8 af2[4], alf2[AT == 2 ? 4 : 1];
#pragma unroll
    for (int i = 0; i < 4; ++i) {
      af2[i] = *(const vec8*)&sA[cur][(wm + 64 + i * 16 + l16) * 32 + cread];
      if constexpr (AT == 2)
        alf2[i] =
            *(const vec8*)&sAl[cur * 8192 + (wm + 64 + i * 16 + l16) * 32 + cread];
    }
    if (st) {
      stageB(b2, t + 2, 0); stageB(b2, t + 2, 1);
      if constexpr (AT == 2) stageAl(b2, t + 2, 1);
    }
    block_bar();
    lgkm0();
    spin();
    __builtin_amdgcn_s_setprio(1);
#pragma unroll
    for (int j = 0; j < 4; ++j)
#pragma unroll
      for (int i = 0; i < 4; ++i) {
        acc[4 + i][j] = mfma8(af2[i], bfr[j], acc[4 + i][j]);
        if constexpr (AT == 2) acc[4 + i][j] = mfma8(alf2[i], bfr[j], acc[4 + i][j]);
      }
    __builtin_amdgcn_s_setprio(0);
    spin();
    if (t + 1 < NT) {
      if (st) vwait<LPT>(); else vwait<0>();
      block_bar();
    }
  };

  if constexpr (UNR) {
    const int NP = NT / 3;   // NT must be divisible by 3
    for (int p = 0; p < NP; ++p) {
      const int t = p * 3;
      tile_step(t + 0, 0, 2);
      tile_step(t + 1, 1, 0);
      tile_step(t + 2, 2, 1);
    }
  } else {
    int cur = 0, b2 = 2;
    for (int t = 0; t < NT; ++t) {
      tile_step(t, cur, b2);
      cur = (cur == 2) ? 0 : cur + 1;
      b2 = (b2 == 2) ? 0 : b2 + 1;
    }
  }

  // C/D frag mapping (m89/m91 verified): col = lane&15, row = quad*4 + reg
  if constexpr (EPI == EPI_F32) {
    float* C = (float*)C0 + (long)z * stC;
#pragma unroll
    for (int i = 0; i < 8; ++i) {
      const int mb = bm + wm + i * 16 + quad * 4;
#pragma unroll
      for (int j = 0; j < 4; ++j) {
        const int n = bn + wn + j * 16 + l16;
#pragma unroll
        for (int r = 0; r < 4; ++r)
          C[(long)(mb + r) * ldc + n] = acc[i][j][r];
      }
    }
  } else if constexpr (EPI == EPI_F16) {
    TO* Ch = (TO*)C0;
#pragma unroll
    for (int i = 0; i < 8; ++i) {
      const int mb = bm + wm + i * 16 + quad * 4;
#pragma unroll
      for (int j = 0; j < 4; ++j) {
        const int n = bn + wn + j * 16 + l16;
#pragma unroll
        for (int r = 0; r < 4; ++r)
          Ch[(long)(mb + r) * ldc + n] = (TO)acc[i][j][r];
      }
    }
  } else {  // EPI_VT
    TO* vT = (TO*)C0;
#pragma unroll
    for (int i = 0; i < 8; ++i) {
      const int mb = bm + wm + i * 16 + quad * 4;
      const long bb = mb >> 11;
      const long ml = mb & 2047;
#pragma unroll
      for (int j = 0; j < 4; ++j) {
        const int e = bn + wn + j * 16 + l16;
        union { TO b[4]; uint2 u; } P;
#pragma unroll
        for (int r = 0; r < 4; ++r) P.b[r] = (TO)acc[i][j][r];
        *(uint2*)&vT[(bb * 768 + e) * 2048 + ml] = P.u;
      }
    }
  }
}

// ---------------------------------------------------------------------------
// 2-phase pipelined GEMM (round-2 verified) — y and v projections.
// ---------------------------------------------------------------------------
template <typename T, typename TO, int BMt, int BNt, int BKt, int AT, int EPI>
__global__ __launch_bounds__((BMt == 256 ? 512 : 256), 2)
void gemm_pipe(const T* __restrict__ Ah, const T* __restrict__ Al,
               const T* __restrict__ Bh, void* __restrict__ C0,
               int K, long lda, long ldb, long ldc,
               long stA, long stB, long stC, int gxN, int gyM) {
  using vec8 = typename std::conditional<std::is_same<T, bf16>::value,
                                         bf16x8, f16x8>::type;
  static_assert(BMt == BNt, "square tiles only");
  constexpr int THREADS = (BMt == 256) ? 512 : 256;
  constexpr int NWN = (BMt == 256) ? 4 : 2;
  constexpr int WTM = BMt / 2;
  constexpr int WTN = BNt / NWN;
  static_assert(WTN == 64, "wave tile must be 64 wide");
  constexpr int MF = WTM / 16;
  constexpr int KK = BKt / 32;
  constexpr int CPR = BKt / 8;
  constexpr int RPI = THREADS / CPR;
  constexpr int LPP = (BMt * BKt) / (THREADS * 8);
  constexpr int LPT = LPP * (AT == 2 ? 3 : 2);

  __shared__ __align__(16) T sA[2][BMt * BKt];
  __shared__ __align__(16) T sB[2][BNt * BKt];
  __shared__ __align__(16) T sAl[AT == 2 ? 2 * BMt * BKt : 8];

  const int id = blockIdx.x;
  const int xcd = id & 7;
  const int j0 = id >> 3;
  const int s = j0 / gxN;
  const int bxi = j0 - s * gxN;
  const int g = xcd + 8 * s;
  const int byi = g % gyM;
  const int z = g / gyM;

  const T* pA = Ah + (long)z * stA;
  const T* pB = Bh + (long)z * stB;
  const T* pAl = (AT == 2) ? Al : nullptr;

  const int bm = byi * BMt;
  const int bn = bxi * BNt;
  const int tid = threadIdx.x;
  const int wave = tid >> 6;
  const int lane = tid & 63;
  const int wm = (wave / NWN) * WTM;
  const int wn = (wave % NWN) * WTN;
  const int quad = lane >> 4;
  const int l16 = lane & 15;

  f32x4 acc[MF][4] = {};

  const int srow = tid / CPR;
  const int schk = tid % CPR;
  const int swc = ((BKt == 64) ? (schk ^ (srow & 7)) : schk) * 8;
  const int cs0 = (quad * 8) ^ ((BKt == 64) ? ((l16 & 7) << 3) : 0);

  const int NT = K / BKt;

  auto stage = [&](int buf, int t) {
    const long ka = (long)t * BKt + swc;
#pragma unroll
    for (int l = 0; l < LPP; ++l)
      async16(pA + (long)(bm + l * RPI + srow) * lda + ka,
              &sA[buf][(l * THREADS + tid) * 8]);
#pragma unroll
    for (int l = 0; l < LPP; ++l)
      async16(pB + (long)(bn + l * RPI + srow) * ldb + ka,
              &sB[buf][(l * THREADS + tid) * 8]);
    if constexpr (AT == 2) {
#pragma unroll
      for (int l = 0; l < LPP; ++l)
        async16(pAl + (long)(bm + l * RPI + srow) * lda + ka,
                &sAl[buf * BMt * BKt + (l * THREADS + tid) * 8]);
    }
  };

  auto compute = [&](int buf) {
    const T* bA = &sA[buf][0];
    const T* bB = &sB[buf][0];
    const T* bAl = (AT == 2) ? &sAl[buf * BMt * BKt] : nullptr;
    vec8 bf[KK][4];
#pragma unroll
    for (int kk = 0; kk < KK; ++kk)
#pragma unroll
      for (int jj = 0; jj < 4; ++jj)
        bf[kk][jj] =
            *(const vec8*)&bB[(wn + jj * 16 + l16) * BKt + (cs0 ^ (kk * 32))];
#pragma unroll
    for (int mq = 0; mq < MF / 2; ++mq) {
      vec8 af[KK][2];
      vec8 alf[AT == 2 ? KK : 1][2];
#pragma unroll
      for (int kk = 0; kk < KK; ++kk)
#pragma unroll
        for (int ii = 0; ii < 2; ++ii) {
          const int r = wm + mq * 32 + ii * 16 + l16;
          af[kk][ii] = *(const vec8*)&bA[r * BKt + (cs0 ^ (kk * 32))];
          if constexpr (AT == 2)
            alf[kk][ii] = *(const vec8*)&bAl[r * BKt + (cs0 ^ (kk * 32))];
        }
      __builtin_amdgcn_s_setprio(1);
#pragma unroll
      for (int jj = 0; jj < 4; ++jj)
#pragma unroll
        for (int ii = 0; ii < 2; ++ii)
#pragma unroll
          for (int kk = 0; kk < KK; ++kk) {
            acc[mq * 2 + ii][jj] =
                mfma8(af[kk][ii], bf[kk][jj], acc[mq * 2 + ii][jj]);
            if constexpr (AT == 2)
              acc[mq * 2 + ii][jj] =
                  mfma8(alf[kk][ii], bf[kk][jj], acc[mq * 2 + ii][jj]);
          }
      __builtin_amdgcn_s_setprio(0);
    }
  };

  stage(0, 0);
  stage(1, 1);
  vwait<LPT>();
  block_bar();

  for (int t = 0; t < NT; ++t) {
    const int cur = t & 1;
    compute(cur);
    if (t + 1 < NT) {
      block_bar();
      if (t + 2 < NT) {
        stage(cur, t + 2);
        vwait<LPT>();
      } else {
        vwait<0>();
      }
      block_bar();
    }
  }

  if constexpr (EPI == EPI_F16) {
    TO* Ch = (TO*)C0;
#pragma unroll
    for (int i = 0; i < MF; ++i) {
      const int mb = bm + wm + i * 16 + quad * 4;
#pragma unroll
      for (int j = 0; j < 4; ++j) {
        const int n = bn + wn + j * 16 + l16;
#pragma unroll
        for (int r = 0; r < 4; ++r)
          Ch[(long)(mb + r) * ldc + n] = (TO)acc[i][j][r];
      }
    }
  } else if constexpr (EPI == EPI_VT) {
    TO* vT = (TO*)C0;
#pragma unroll
    for (int i = 0; i < MF; ++i) {
      const int mb = bm + wm + i * 16 + quad * 4;
      const long bb = mb >> 11;
      const long ml = mb & 2047;
#pragma unroll
      for (int j = 0; j < 4; ++j) {
        const int e = bn + wn + j * 16 + l16;
        union { TO b[4]; uint2 u; } P;
#pragma unroll
        for (int r = 0; r < 4; ++r) P.b[r] = (TO)acc[i][j][r];
        *(uint2*)&vT[(bb * 768 + e) * 2048 + ml] = P.u;
      }
    }
  } else {  // EPI_F32
    float* C = (float*)C0 + (long)z * stC;
#pragma unroll
    for (int i = 0; i < MF; ++i) {
      const int mb = bm + wm + i * 16 + quad * 4;
#pragma unroll
      for (int j = 0; j < 4; ++j) {
        const int n = bn + wn + j * 16 + l16;
#pragma unroll
        for (int r = 0; r < 4; ++r)
          C[(long)(mb + r) * ldc + n] = acc[i][j][r];
      }
    }
  }
}

// ---------------------------------------------------------------------------
// Old 128x128/BK64 drain kernel (verified) — kept for the small Mt GEMM only.
// ---------------------------------------------------------------------------
constexpr int BM = 128, BN = 128, BK = 64;

template <typename T, typename TO, int AT, int BT, int EPI, int SWZ>
__global__ __launch_bounds__(256)
void gemm_kernel(const T* __restrict__ Ah, const T* __restrict__ Al,
                 const T* __restrict__ Bh, const T* __restrict__ Bl,
                 void* __restrict__ C0, void* __restrict__ C1,
                 int K, long lda, long ldb, long ldbl, long ldc,
                 long stA, long stB, long stBl, long stC,
                 int gxN, int gyM) {
  using vec8 = typename std::conditional<std::is_same<T, bf16>::value,
                                         bf16x8, f16x8>::type;
  __shared__ __align__(16) T sAh[BM * BK];
  __shared__ __align__(16) T sBh[BN * BK];
  __shared__ __align__(16) T sAl[AT == 2 ? BM * BK : 8];
  __shared__ __align__(16) T sBl[BT == 2 ? BN * BK : 8];

  int bxi, byi, z;
  if constexpr (SWZ) {
    const int id = blockIdx.x;
    const int xcd = id & 7;
    const int j = id >> 3;
    const int s = j / gxN;
    const int n = j - s * gxN;
    const int g = xcd + 8 * s;
    bxi = n;
    byi = g % gyM;
    z = g / gyM;
  } else {
    bxi = blockIdx.x; byi = blockIdx.y; z = blockIdx.z;
  }

  const T* pAh = Ah + (long)z * stA;
  const T* pBh = Bh + (long)z * stB;
  const T* pAl = (AT == 2) ? (Al + (long)z * stA) : nullptr;
  const T* pBl = (BT == 2) ? (Bl + (long)z * stBl) : nullptr;

  const int bm = byi * BM;
  const int bn = bxi * BN;
  const int tid = threadIdx.x;
  const int wave = tid >> 6;
  const int lane = tid & 63;
  const int wm = (wave & 1) * 64;
  const int wn = (wave >> 1) * 64;
  const int quad = lane >> 4;
  const int l16 = lane & 15;

  f32x4 acc[4][4] = {};

  const int sr0 = tid >> 3;
  const int swc = ((tid & 7) ^ (sr0 & 7)) * 8;
  const int cs0 = (quad * 8) ^ ((l16 & 7) << 3);

  for (int kt = 0; kt < K; kt += BK) {
    __syncthreads();
    {
      const long ka = kt + swc;
#pragma unroll
      for (int l = 0; l < 4; ++l) {
        const int row = l * 32 + sr0;
        async16(pAh + (long)(bm + row) * lda + ka, &sAh[(l * 256 + tid) * 8]);
      }
#pragma unroll
      for (int l = 0; l < 4; ++l) {
        const int row = l * 32 + sr0;
        async16(pBh + (long)(bn + row) * ldb + ka, &sBh[(l * 256 + tid) * 8]);
      }
      if constexpr (AT == 2) {
#pragma unroll
        for (int l = 0; l < 4; ++l) {
          const int row = l * 32 + sr0;
          async16(pAl + (long)(bm + row) * lda + ka, &sAl[(l * 256 + tid) * 8]);
        }
      }
      if constexpr (BT == 2) {
#pragma unroll
        for (int l = 0; l < 4; ++l) {
          const int row = l * 32 + sr0;
          async16(pBl + (long)(bn + row) * ldbl + ka, &sBl[(l * 256 + tid) * 8]);
        }
      }
    }
    __syncthreads();

#pragma unroll
    for (int kk = 0; kk < 2; ++kk) {
      const int cs = cs0 ^ (kk * 32);
      vec8 ah[4], al[4];
#pragma unroll
      for (int i = 0; i < 4; ++i) {
        ah[i] = *(const vec8*)&sAh[(wm + i * 16 + l16) * BK + cs];
        if constexpr (AT == 2)
          al[i] = *(const vec8*)&sAl[(wm + i * 16 + l16) * BK + cs];
      }
#pragma unroll
      for (int j = 0; j < 4; ++j) {
        const vec8 bh = *(const vec8*)&sBh[(wn + j * 16 + l16) * BK + cs];
        vec8 bl;
        if constexpr (BT == 2)
          bl = *(const vec8*)&sBl[(wn + j * 16 + l16) * BK + cs];
#pragma unroll
        for (int i = 0; i < 4; ++i) {
          acc[i][j] = mfma8(ah[i], bh, acc[i][j]);
          if constexpr (BT == 2) acc[i][j] = mfma8(ah[i], bl, acc[i][j]);
          if constexpr (AT == 2) acc[i][j] = mfma8(al[i], bh, acc[i][j]);
        }
      }
    }
  }

  if constexpr (EPI == EPI_PAIR) {
    TO* Ch = (TO*)C0;
    TO* Cl = (TO*)C1;
#pragma unroll
    for (int i = 0; i < 4; ++i) {
      const int mb = bm + wm + i * 16 + quad * 4;
#pragma unroll
      for (int j = 0; j < 4; ++j) {
        const int n = bn + wn + j * 16 + l16;
#pragma unroll
        for (int r = 0; r < 4; ++r) {
          const float f = acc[i][j][r];
          const TO h = (TO)f;
          const long idx = (long)(mb + r) * ldc + n;
          Ch[idx] = h;
          Cl[idx] = (TO)(f - (float)h);
        }
      }
    }
  }
}

// One block per score row (2048 fp32). Writes normalized p * (1/sqrt(768)) as
// f16 IN-PLACE into the first quarter of the row's fp32 storage.
__global__ __launch_bounds__(256)
void softmax_kernel(float* __restrict__ sc) {
  __shared__ float red[4];
  float* srow = sc + (long)blockIdx.x * 2048;
  const int tid = threadIdx.x;
  const int wave = tid >> 6;
  const int lane = tid & 63;
  const float4 v0 = *(const float4*)(srow + tid * 4);
  const float4 v1 = *(const float4*)(srow + 1024 + tid * 4);
  float mx = fmaxf(fmaxf(fmaxf(v0.x, v0.y), fmaxf(v0.z, v0.w)),
                   fmaxf(fmaxf(v1.x, v1.y), fmaxf(v1.z, v1.w)));
#pragma unroll
  for (int o = 32; o >= 1; o >>= 1) mx = fmaxf(mx, __shfl_xor(mx, o));
  if (lane == 0) red[wave] = mx;
  __syncthreads();
  mx = fmaxf(fmaxf(red[0], red[1]), fmaxf(red[2], red[3]));
  const float e0 = exp2f((v0.x - mx) * LOG2E);
  const float e1 = exp2f((v0.y - mx) * LOG2E);
  const float e2 = exp2f((v0.z - mx) * LOG2E);
  const float e3 = exp2f((v0.w - mx) * LOG2E);
  const float e4 = exp2f((v1.x - mx) * LOG2E);
  const float e5 = exp2f((v1.y - mx) * LOG2E);
  const float e6 = exp2f((v1.z - mx) * LOG2E);
  const float e7 = exp2f((v1.w - mx) * LOG2E);
  float s = ((e0 + e1) + (e2 + e3)) + ((e4 + e5) + (e6 + e7));
#pragma unroll
  for (int o = 32; o >= 1; o >>= 1) s += __shfl_xor(s, o);
  __syncthreads();
  if (lane == 0) red[wave] = s;
  __syncthreads();
  s = red[0] + red[1] + red[2] + red[3];
  const float inv = 1.0f / (s * SQRT_E);
  f16* prow = (f16*)srow;
  union { f16 b[4]; uint2 u; } P;
  P.b[0] = (f16)(e0 * inv); P.b[1] = (f16)(e1 * inv);
  P.b[2] = (f16)(e2 * inv); P.b[3] = (f16)(e3 * inv);
  *(uint2*)(prow + tid * 4) = P.u;
  P.b[0] = (f16)(e4 * inv); P.b[1] = (f16)(e5 * inv);
  P.b[2] = (f16)(e6 * inv); P.b[3] = (f16)(e7 * inv);
  *(uint2*)(prow + 1024 + tid * 4) = P.u;
}

// Fused fp32 -> f16: x -> hi/lo pair; Wv -> single.
__global__ __launch_bounds__(256)
void split_all(const float4* __restrict__ x, const float4* __restrict__ wv,
               uint2* __restrict__ xh, uint2* __restrict__ xl,
               uint2* __restrict__ wvh) {
  constexpr int NX = 3145728;
  constexpr int NWV = 147456;
  const int i = blockIdx.x * 256 + threadIdx.x;
  float4 v;
  uint2 *dh, *dl;
  if (i < NX) {
    v = x[i]; dh = xh + i; dl = xl + i;
  } else {
    const int m = i - NX;
    if (m >= NWV) return;
    v = wv[m]; dh = wvh + m; dl = nullptr;
  }
  const f16 h0 = (f16)v.x, h1 = (f16)v.y, h2 = (f16)v.z, h3 = (f16)v.w;
  union { f16 b[4]; uint2 u; } P;
  P.b[0] = h0; P.b[1] = h1; P.b[2] = h2; P.b[3] = h3;
  *dh = P.u;
  if (dl != nullptr) {
    P.b[0] = (f16)(v.x - (float)h0);
    P.b[1] = (f16)(v.y - (float)h1);
    P.b[2] = (f16)(v.z - (float)h2);
    P.b[3] = (f16)(v.w - (float)h3);
    *dl = P.u;
  }
}

// Transpose 768x768 fp32 W[e][d] -> f16 hi/lo pair WT[d][e] (e contiguous).
__global__ __launch_bounds__(256)
void transpose_split(const float* __restrict__ Wq, const float* __restrict__ Wk,
                     f16* __restrict__ qTh, f16* __restrict__ qTl,
                     f16* __restrict__ kTh, f16* __restrict__ kTl) {
  __shared__ float tile[64][65];
  const float* src = blockIdx.z ? Wk : Wq;
  f16* dh = blockIdx.z ? kTh : qTh;
  f16* dl = blockIdx.z ? kTl : qTl;
  const int e0 = blockIdx.y * 64, d0 = blockIdx.x * 64;
  const int t = threadIdx.x;
  const int r = t >> 2;
  const int c4 = (t & 3) * 16;
  const float4* s4 = (const float4*)(src + (long)(e0 + r) * 768 + d0 + c4);
#pragma unroll
  for (int g = 0; g < 4; ++g) {
    const float4 v = s4[g];
    tile[r][c4 + g * 4 + 0] = v.x;
    tile[r][c4 + g * 4 + 1] = v.y;
    tile[r][c4 + g * 4 + 2] = v.z;
    tile[r][c4 + g * 4 + 3] = v.w;
  }
  __syncthreads();
  union { f16 b[8]; uint4 u; } H0, H1, L0, L1;
#pragma unroll
  for (int i = 0; i < 16; ++i) {
    const float v = tile[c4 + i][r];
    const f16 h = (f16)v;
    const f16 l = (f16)(v - (float)h);
    if (i < 8) { H0.b[i] = h; L0.b[i] = l; }
    else       { H1.b[i - 8] = h; L1.b[i - 8] = l; }
  }
  const long o = (long)(d0 + r) * 768 + e0 + c4;
  *(uint4*)(dh + o) = H0.u;  *(uint4*)(dh + o + 8) = H1.u;
  *(uint4*)(dl + o) = L0.u;  *(uint4*)(dl + o + 8) = L1.u;
}

extern "C" void kernel_launch(void* const* d_in, const int* in_sizes, int n_in,
                              void* d_out, int out_size, void* d_ws, size_t ws_size,
                              hipStream_t stream) {
  const float* x  = (const float*)d_in[0];
  const float* Wq = (const float*)d_in[1];
  const float* Wk = (const float*)d_in[2];
  const float* Wv = (const float*)d_in[3];
  float* out = (float*)d_out;
  char* ws = (char*)d_ws;

  // ---- workspace layout (bytes) ----
  const size_t SZ = 25165824;      // 16384*768*2
  f16* yh = (f16*)(ws + 0 * SZ);
  f16* xh = (f16*)(ws + 2 * SZ);
  f16* vT = (f16*)(ws + 3 * SZ);
  const size_t PERS = 4 * SZ;      // 100663296
  const size_t WT = 1179648;       // 768*768 f16
  f16* xl   = (f16*)(ws + PERS);
  f16* wqTh = (f16*)(ws + PERS + SZ);
  f16* wqTl = (f16*)(ws + PERS + SZ + 1 * WT);
  f16* wkTh = (f16*)(ws + PERS + SZ + 2 * WT);
  f16* wkTl = (f16*)(ws + PERS + SZ + 3 * WT);
  f16* mtH  = (f16*)(ws + PERS + SZ + 4 * WT);
  f16* mtL  = (f16*)(ws + PERS + SZ + 5 * WT);
  f16* wvh  = (f16*)(ws + PERS + SZ + 6 * WT);
  float* scores = (float*)(ws + PERS);

  long avail = (long)ws_size - (long)PERS;
  int nb = (int)(avail / 16777216);
  if (nb < 1) nb = 1;
  if (nb > 8) nb = 8;

  // ---- phase 1 ----
  split_all<<<12864, 256, 0, stream>>>(
      (const float4*)x, (const float4*)Wv, (uint2*)xh, (uint2*)xl, (uint2*)wvh);
  transpose_split<<<dim3(12, 12, 2), 256, 0, stream>>>(
      Wq, Wk, wqTh, wqTl, wkTh, wkTl);

  // M^T[d'][d] = sum_e WkT[d'][e] * WqT[d][e]  (3-term, f16 pair out)
  gemm_kernel<f16, f16, 2, 2, EPI_PAIR, 0><<<dim3(6, 6, 1), 256, 0, stream>>>(
      wkTh, wkTl, wqTh, wqTl, (void*)mtH, (void*)mtL,
      768, 768, 768, 768, 768, 0, 0, 0, 0, 0, 0);

  // y = (xh+xl) * MT_h^T : f16 hi only, 2-term, BK32 dbuf
  gemm_pipe<f16, f16, 128, 128, 32, 2, EPI_F16><<<768, 256, 0, stream>>>(
      xh, xl, mtH, (void*)yh, 768, 768, 768, 768, 0, 0, 0, 6, 128);

  // v = xh * Wv_h^T -> vT f16 transposed, 1-term, BK64 dbuf
  gemm_pipe<f16, f16, 128, 128, 64, 1, EPI_VT><<<768, 256, 0, stream>>>(
      xh, nullptr, wvh, (void*)vT, 768, 768, 768, 0, 0, 0, 0, 6, 128);

  // ---- phase 2: scores -> softmax -> PV ----
  const long RS = 1572864;   // 2048*768
  const long VTS = 1572864;  // 768*2048
  for (int b0 = 0; b0 < 8; b0 += nb) {
    const int nbg = (8 - b0 < nb) ? (8 - b0) : nb;
    // S = yh * xh^T : 256^2 ring, z-major, STATIC x3-unrolled (NT=24)
    gemm_ring<f16, float, 1, EPI_F32, 1><<<64 * nbg, 512, 0, stream>>>(
        yh + (long)b0 * RS, nullptr, xh + (long)b0 * RS, (void*)scores,
        768, 768, 768, 2048, RS, RS, 4194304L, 8, 8, nbg);
    softmax_kernel<<<nbg * 2048, 256, 0, stream>>>(scores);
    // O = P * vT^T : 256^2 ring, dynamic (NT=64 not divisible by 3)
    gemm_ring<f16, float, 1, EPI_F32, 0><<<24 * nbg, 512, 0, stream>>>(
        (const f16*)scores, nullptr, vT + (long)b0 * VTS,
        (void*)(out + (long)b0 * 1572864),
        2048, 4096, 2048, 768, 8388608L, VTS, 1572864L, 3, 8, nbg);
  }
}

// Round 12
// 367.977 us; speedup vs baseline: 1.1540x; 1.0368x over previous
//
#include <hip/hip_runtime.h>
#include <stdint.h>
#include <type_traits>

typedef __bf16 bf16;
typedef _Float16 f16;
typedef bf16 bf16x8 __attribute__((ext_vector_type(8)));
typedef f16 f16x8 __attribute__((ext_vector_type(8)));
typedef float f32x4 __attribute__((ext_vector_type(4)));

#define LOG2E 1.4426950408889634f
#define SQRT_E 27.712812921102035f

enum { EPI_F32 = 0, EPI_PAIR = 1, EPI_VT = 2, EPI_F16 = 3 };

__device__ __forceinline__ void async16(const void* g, void* l) {
  __builtin_amdgcn_global_load_lds(
      (__attribute__((address_space(1))) void*)(uintptr_t)g,
      (__attribute__((address_space(3))) void*)l, 16, 0, 0);
}

__device__ __forceinline__ f32x4 mfma8(bf16x8 a, bf16x8 b, f32x4 c) {
  return __builtin_amdgcn_mfma_f32_16x16x32_bf16(a, b, c, 0, 0, 0);
}
__device__ __forceinline__ f32x4 mfma8(f16x8 a, f16x8 b, f32x4 c) {
  return __builtin_amdgcn_mfma_f32_16x16x32_f16(a, b, c, 0, 0, 0);
}

template <int N>
__device__ __forceinline__ void vwait() {
  asm volatile("s_waitcnt vmcnt(%0)" ::"i"(N) : "memory");
}
__device__ __forceinline__ void block_bar() {
  asm volatile("" ::: "memory");
  __builtin_amdgcn_s_barrier();
  asm volatile("" ::: "memory");
}
__device__ __forceinline__ void lgkm0() {
  asm volatile("s_waitcnt lgkmcnt(0)" ::: "memory");
}
__device__ __forceinline__ void spin() { __builtin_amdgcn_sched_barrier(0); }

// ---------------------------------------------------------------------------
// Fine-phase ring GEMM (round-3 verified schedule): C[M,N] = A[M,K]*B[N,K]^T.
// 256x256 tile, BK=32, 512 threads (8 waves 2Mx4N, wave tile 128x64),
// 3-buffer LDS ring. Per tile t: two phases, each {ds_read frags; stage 2
// loads of t+2; BAR; lgkm0; setprio; 16 MFMA; setprio; BAR}; counted
// vwait<LPT> at tile end (t+2's loads stay in flight). BK=32 chunk-XOR
// swizzle both sides (0 conflicts, HW-verified). z-major decode (nz>0): one
// batch per XCD (FETCH 110->37 MB, HW-verified).
// UNR=1 (static x3 unroll) measured NULL vs UNR=0 (round 11: S 76us both);
// UNR=0 used for bit-fidelity with the verified 366us configuration.
// ---------------------------------------------------------------------------
template <typename T, typename TO, int AT, int EPI, int UNR>
__global__ __launch_bounds__(512, 2)
void gemm_ring(const T* __restrict__ Ah, const T* __restrict__ Al,
               const T* __restrict__ Bh, void* __restrict__ C0,
               int K, long lda, long ldb, long ldc,
               long stA, long stB, long stC, int gxN, int gyM, int nz) {
  using vec8 = typename std::conditional<std::is_same<T, bf16>::value,
                                         bf16x8, f16x8>::type;
  constexpr int LPT = (AT == 2) ? 6 : 4;
  __shared__ __align__(16) T sA[3][256 * 32];
  __shared__ __align__(16) T sB[3][256 * 32];
  __shared__ __align__(16) T sAl[AT == 2 ? 3 * 256 * 32 : 8];

  const int id = blockIdx.x;
  const int xcd = id & 7;
  const int j0 = id >> 3;
  const int s = j0 / gxN;
  const int bxi = j0 - s * gxN;
  const int g = xcd + 8 * s;
  int byi, z;
  if (nz > 0) { z = g % nz; byi = g / nz; }
  else        { byi = g % gyM; z = g / gyM; }

  const T* pA = Ah + (long)z * stA;
  const T* pB = Bh + (long)z * stB;
  const T* pAl = (AT == 2) ? Al : nullptr;

  const int bm = byi * 256;
  const int bn = bxi * 256;
  const int tid = threadIdx.x;
  const int wave = tid >> 6;
  const int lane = tid & 63;
  const int wm = (wave >> 2) * 128;
  const int wn = (wave & 3) * 64;
  const int quad = lane >> 4;
  const int l16 = lane & 15;

  f32x4 acc[8][4] = {};

  const int srow = tid >> 2;
  const int swc = ((tid & 3) ^ ((tid >> 3) & 3)) * 8;
  const int cread = (quad ^ ((l16 >> 1) & 3)) * 8;

  const int NT = K / 32;

  auto stageA = [&](int buf, int t, int l) {
    const long ka = (long)t * 32 + swc;
    async16(pA + (long)(bm + l * 128 + srow) * lda + ka,
            &sA[buf][(l * 512 + tid) * 8]);
  };
  auto stageB = [&](int buf, int t, int l) {
    const long ka = (long)t * 32 + swc;
    async16(pB + (long)(bn + l * 128 + srow) * ldb + ka,
            &sB[buf][(l * 512 + tid) * 8]);
  };
  auto stageAl = [&](int buf, int t, int l) {
    const long ka = (long)t * 32 + swc;
    async16(pAl + (long)(bm + l * 128 + srow) * lda + ka,
            &sAl[buf * 8192 + (l * 512 + tid) * 8]);
  };

  stageA(0, 0, 0); stageA(0, 0, 1); stageB(0, 0, 0); stageB(0, 0, 1);
  if constexpr (AT == 2) { stageAl(0, 0, 0); stageAl(0, 0, 1); }
  stageA(1, 1, 0); stageA(1, 1, 1); stageB(1, 1, 0); stageB(1, 1, 1);
  if constexpr (AT == 2) { stageAl(1, 1, 0); stageAl(1, 1, 1); }
  vwait<LPT>();
  block_bar();

  auto tile_step = [&](int t, int cur, int b2) {
    const bool st = (t + 2 < NT);
    vec8 bfr[4], af[4], alf[AT == 2 ? 4 : 1];
#pragma unroll
    for (int j = 0; j < 4; ++j)
      bfr[j] = *(const vec8*)&sB[cur][(wn + j * 16 + l16) * 32 + cread];
#pragma unroll
    for (int i = 0; i < 4; ++i) {
      af[i] = *(const vec8*)&sA[cur][(wm + i * 16 + l16) * 32 + cread];
      if constexpr (AT == 2)
        alf[i] = *(const vec8*)&sAl[cur * 8192 + (wm + i * 16 + l16) * 32 + cread];
    }
    if (st) {
      stageA(b2, t + 2, 0); stageA(b2, t + 2, 1);
      if constexpr (AT == 2) stageAl(b2, t + 2, 0);
    }
    block_bar();
    lgkm0();
    spin();
    __builtin_amdgcn_s_setprio(1);
#pragma unroll
    for (int j = 0; j < 4; ++j)
#pragma unroll
      for (int i = 0; i < 4; ++i) {
        acc[i][j] = mfma8(af[i], bfr[j], acc[i][j]);
        if constexpr (AT == 2) acc[i][j] = mfma8(alf[i], bfr[j], acc[i][j]);
      }
    __builtin_amdgcn_s_setprio(0);
    spin();
    block_bar();
    vec8 af2[4], alf2[AT == 2 ? 4 : 1];
#pragma unroll
    for (int i = 0; i < 4; ++i) {
      af2[i] = *(const vec8*)&sA[cur][(wm + 64 + i * 16 + l16) * 32 + cread];
      if constexpr (AT == 2)
        alf2[i] =
            *(const vec8*)&sAl[cur * 8192 + (wm + 64 + i * 16 + l16) * 32 + cread];
    }
    if (st) {
      stageB(b2, t + 2, 0); stageB(b2, t + 2, 1);
      if constexpr (AT == 2) stageAl(b2, t + 2, 1);
    }
    block_bar();
    lgkm0();
    spin();
    __builtin_amdgcn_s_setprio(1);
#pragma unroll
    for (int j = 0; j < 4; ++j)
#pragma unroll
      for (int i = 0; i < 4; ++i) {
        acc[4 + i][j] = mfma8(af2[i], bfr[j], acc[4 + i][j]);
        if constexpr (AT == 2) acc[4 + i][j] = mfma8(alf2[i], bfr[j], acc[4 + i][j]);
      }
    __builtin_amdgcn_s_setprio(0);
    spin();
    if (t + 1 < NT) {
      if (st) vwait<LPT>(); else vwait<0>();
      block_bar();
    }
  };

  if constexpr (UNR) {
    const int NP = NT / 3;
    for (int p = 0; p < NP; ++p) {
      const int t = p * 3;
      tile_step(t + 0, 0, 2);
      tile_step(t + 1, 1, 0);
      tile_step(t + 2, 2, 1);
    }
  } else {
    int cur = 0, b2 = 2;
    for (int t = 0; t < NT; ++t) {
      tile_step(t, cur, b2);
      cur = (cur == 2) ? 0 : cur + 1;
      b2 = (b2 == 2) ? 0 : b2 + 1;
    }
  }

  // C/D frag mapping (m89/m91 verified): col = lane&15, row = quad*4 + reg
  if constexpr (EPI == EPI_F32) {
    float* C = (float*)C0 + (long)z * stC;
#pragma unroll
    for (int i = 0; i < 8; ++i) {
      const int mb = bm + wm + i * 16 + quad * 4;
#pragma unroll
      for (int j = 0; j < 4; ++j) {
        const int n = bn + wn + j * 16 + l16;
#pragma unroll
        for (int r = 0; r < 4; ++r)
          C[(long)(mb + r) * ldc + n] = acc[i][j][r];
      }
    }
  } else if constexpr (EPI == EPI_F16) {
    TO* Ch = (TO*)C0;
#pragma unroll
    for (int i = 0; i < 8; ++i) {
      const int mb = bm + wm + i * 16 + quad * 4;
#pragma unroll
      for (int j = 0; j < 4; ++j) {
        const int n = bn + wn + j * 16 + l16;
#pragma unroll
        for (int r = 0; r < 4; ++r)
          Ch[(long)(mb + r) * ldc + n] = (TO)acc[i][j][r];
      }
    }
  } else {  // EPI_VT
    TO* vT = (TO*)C0;
#pragma unroll
    for (int i = 0; i < 8; ++i) {
      const int mb = bm + wm + i * 16 + quad * 4;
      const long bb = mb >> 11;
      const long ml = mb & 2047;
#pragma unroll
      for (int j = 0; j < 4; ++j) {
        const int e = bn + wn + j * 16 + l16;
        union { TO b[4]; uint2 u; } P;
#pragma unroll
        for (int r = 0; r < 4; ++r) P.b[r] = (TO)acc[i][j][r];
        *(uint2*)&vT[(bb * 768 + e) * 2048 + ml] = P.u;
      }
    }
  }
}

// ---------------------------------------------------------------------------
// 2-phase pipelined GEMM (round-2 verified) — y and v projections.
// ---------------------------------------------------------------------------
template <typename T, typename TO, int BMt, int BNt, int BKt, int AT, int EPI>
__global__ __launch_bounds__((BMt == 256 ? 512 : 256), 2)
void gemm_pipe(const T* __restrict__ Ah, const T* __restrict__ Al,
               const T* __restrict__ Bh, void* __restrict__ C0,
               int K, long lda, long ldb, long ldc,
               long stA, long stB, long stC, int gxN, int gyM) {
  using vec8 = typename std::conditional<std::is_same<T, bf16>::value,
                                         bf16x8, f16x8>::type;
  static_assert(BMt == BNt, "square tiles only");
  constexpr int THREADS = (BMt == 256) ? 512 : 256;
  constexpr int NWN = (BMt == 256) ? 4 : 2;
  constexpr int WTM = BMt / 2;
  constexpr int WTN = BNt / NWN;
  static_assert(WTN == 64, "wave tile must be 64 wide");
  constexpr int MF = WTM / 16;
  constexpr int KK = BKt / 32;
  constexpr int CPR = BKt / 8;
  constexpr int RPI = THREADS / CPR;
  constexpr int LPP = (BMt * BKt) / (THREADS * 8);
  constexpr int LPT = LPP * (AT == 2 ? 3 : 2);

  __shared__ __align__(16) T sA[2][BMt * BKt];
  __shared__ __align__(16) T sB[2][BNt * BKt];
  __shared__ __align__(16) T sAl[AT == 2 ? 2 * BMt * BKt : 8];

  const int id = blockIdx.x;
  const int xcd = id & 7;
  const int j0 = id >> 3;
  const int s = j0 / gxN;
  const int bxi = j0 - s * gxN;
  const int g = xcd + 8 * s;
  const int byi = g % gyM;
  const int z = g / gyM;

  const T* pA = Ah + (long)z * stA;
  const T* pB = Bh + (long)z * stB;
  const T* pAl = (AT == 2) ? Al : nullptr;

  const int bm = byi * BMt;
  const int bn = bxi * BNt;
  const int tid = threadIdx.x;
  const int wave = tid >> 6;
  const int lane = tid & 63;
  const int wm = (wave / NWN) * WTM;
  const int wn = (wave % NWN) * WTN;
  const int quad = lane >> 4;
  const int l16 = lane & 15;

  f32x4 acc[MF][4] = {};

  const int srow = tid / CPR;
  const int schk = tid % CPR;
  const int swc = ((BKt == 64) ? (schk ^ (srow & 7)) : schk) * 8;
  const int cs0 = (quad * 8) ^ ((BKt == 64) ? ((l16 & 7) << 3) : 0);

  const int NT = K / BKt;

  auto stage = [&](int buf, int t) {
    const long ka = (long)t * BKt + swc;
#pragma unroll
    for (int l = 0; l < LPP; ++l)
      async16(pA + (long)(bm + l * RPI + srow) * lda + ka,
              &sA[buf][(l * THREADS + tid) * 8]);
#pragma unroll
    for (int l = 0; l < LPP; ++l)
      async16(pB + (long)(bn + l * RPI + srow) * ldb + ka,
              &sB[buf][(l * THREADS + tid) * 8]);
    if constexpr (AT == 2) {
#pragma unroll
      for (int l = 0; l < LPP; ++l)
        async16(pAl + (long)(bm + l * RPI + srow) * lda + ka,
                &sAl[buf * BMt * BKt + (l * THREADS + tid) * 8]);
    }
  };

  auto compute = [&](int buf) {
    const T* bA = &sA[buf][0];
    const T* bB = &sB[buf][0];
    const T* bAl = (AT == 2) ? &sAl[buf * BMt * BKt] : nullptr;
    vec8 bf[KK][4];
#pragma unroll
    for (int kk = 0; kk < KK; ++kk)
#pragma unroll
      for (int jj = 0; jj < 4; ++jj)
        bf[kk][jj] =
            *(const vec8*)&bB[(wn + jj * 16 + l16) * BKt + (cs0 ^ (kk * 32))];
#pragma unroll
    for (int mq = 0; mq < MF / 2; ++mq) {
      vec8 af[KK][2];
      vec8 alf[AT == 2 ? KK : 1][2];
#pragma unroll
      for (int kk = 0; kk < KK; ++kk)
#pragma unroll
        for (int ii = 0; ii < 2; ++ii) {
          const int r = wm + mq * 32 + ii * 16 + l16;
          af[kk][ii] = *(const vec8*)&bA[r * BKt + (cs0 ^ (kk * 32))];
          if constexpr (AT == 2)
            alf[kk][ii] = *(const vec8*)&bAl[r * BKt + (cs0 ^ (kk * 32))];
        }
      __builtin_amdgcn_s_setprio(1);
#pragma unroll
      for (int jj = 0; jj < 4; ++jj)
#pragma unroll
        for (int ii = 0; ii < 2; ++ii)
#pragma unroll
          for (int kk = 0; kk < KK; ++kk) {
            acc[mq * 2 + ii][jj] =
                mfma8(af[kk][ii], bf[kk][jj], acc[mq * 2 + ii][jj]);
            if constexpr (AT == 2)
              acc[mq * 2 + ii][jj] =
                  mfma8(alf[kk][ii], bf[kk][jj], acc[mq * 2 + ii][jj]);
          }
      __builtin_amdgcn_s_setprio(0);
    }
  };

  stage(0, 0);
  stage(1, 1);
  vwait<LPT>();
  block_bar();

  for (int t = 0; t < NT; ++t) {
    const int cur = t & 1;
    compute(cur);
    if (t + 1 < NT) {
      block_bar();
      if (t + 2 < NT) {
        stage(cur, t + 2);
        vwait<LPT>();
      } else {
        vwait<0>();
      }
      block_bar();
    }
  }

  if constexpr (EPI == EPI_F16) {
    TO* Ch = (TO*)C0;
#pragma unroll
    for (int i = 0; i < MF; ++i) {
      const int mb = bm + wm + i * 16 + quad * 4;
#pragma unroll
      for (int j = 0; j < 4; ++j) {
        const int n = bn + wn + j * 16 + l16;
#pragma unroll
        for (int r = 0; r < 4; ++r)
          Ch[(long)(mb + r) * ldc + n] = (TO)acc[i][j][r];
      }
    }
  } else if constexpr (EPI == EPI_VT) {
    TO* vT = (TO*)C0;
#pragma unroll
    for (int i = 0; i < MF; ++i) {
      const int mb = bm + wm + i * 16 + quad * 4;
      const long bb = mb >> 11;
      const long ml = mb & 2047;
#pragma unroll
      for (int j = 0; j < 4; ++j) {
        const int e = bn + wn + j * 16 + l16;
        union { TO b[4]; uint2 u; } P;
#pragma unroll
        for (int r = 0; r < 4; ++r) P.b[r] = (TO)acc[i][j][r];
        *(uint2*)&vT[(bb * 768 + e) * 2048 + ml] = P.u;
      }
    }
  } else {  // EPI_F32
    float* C = (float*)C0 + (long)z * stC;
#pragma unroll
    for (int i = 0; i < MF; ++i) {
      const int mb = bm + wm + i * 16 + quad * 4;
#pragma unroll
      for (int j = 0; j < 4; ++j) {
        const int n = bn + wn + j * 16 + l16;
#pragma unroll
        for (int r = 0; r < 4; ++r)
          C[(long)(mb + r) * ldc + n] = acc[i][j][r];
      }
    }
  }
}

// ---------------------------------------------------------------------------
// Old 128x128/BK64 drain kernel (verified) — kept for the small Mt GEMM only.
// ---------------------------------------------------------------------------
constexpr int BM = 128, BN = 128, BK = 64;

template <typename T, typename TO, int AT, int BT, int EPI, int SWZ>
__global__ __launch_bounds__(256)
void gemm_kernel(const T* __restrict__ Ah, const T* __restrict__ Al,
                 const T* __restrict__ Bh, const T* __restrict__ Bl,
                 void* __restrict__ C0, void* __restrict__ C1,
                 int K, long lda, long ldb, long ldbl, long ldc,
                 long stA, long stB, long stBl, long stC,
                 int gxN, int gyM) {
  using vec8 = typename std::conditional<std::is_same<T, bf16>::value,
                                         bf16x8, f16x8>::type;
  __shared__ __align__(16) T sAh[BM * BK];
  __shared__ __align__(16) T sBh[BN * BK];
  __shared__ __align__(16) T sAl[AT == 2 ? BM * BK : 8];
  __shared__ __align__(16) T sBl[BT == 2 ? BN * BK : 8];

  int bxi, byi, z;
  if constexpr (SWZ) {
    const int id = blockIdx.x;
    const int xcd = id & 7;
    const int j = id >> 3;
    const int s = j / gxN;
    const int n = j - s * gxN;
    const int g = xcd + 8 * s;
    bxi = n;
    byi = g % gyM;
    z = g / gyM;
  } else {
    bxi = blockIdx.x; byi = blockIdx.y; z = blockIdx.z;
  }

  const T* pAh = Ah + (long)z * stA;
  const T* pBh = Bh + (long)z * stB;
  const T* pAl = (AT == 2) ? (Al + (long)z * stA) : nullptr;
  const T* pBl = (BT == 2) ? (Bl + (long)z * stBl) : nullptr;

  const int bm = byi * BM;
  const int bn = bxi * BN;
  const int tid = threadIdx.x;
  const int wave = tid >> 6;
  const int lane = tid & 63;
  const int wm = (wave & 1) * 64;
  const int wn = (wave >> 1) * 64;
  const int quad = lane >> 4;
  const int l16 = lane & 15;

  f32x4 acc[4][4] = {};

  const int sr0 = tid >> 3;
  const int swc = ((tid & 7) ^ (sr0 & 7)) * 8;
  const int cs0 = (quad * 8) ^ ((l16 & 7) << 3);

  for (int kt = 0; kt < K; kt += BK) {
    __syncthreads();
    {
      const long ka = kt + swc;
#pragma unroll
      for (int l = 0; l < 4; ++l) {
        const int row = l * 32 + sr0;
        async16(pAh + (long)(bm + row) * lda + ka, &sAh[(l * 256 + tid) * 8]);
      }
#pragma unroll
      for (int l = 0; l < 4; ++l) {
        const int row = l * 32 + sr0;
        async16(pBh + (long)(bn + row) * ldb + ka, &sBh[(l * 256 + tid) * 8]);
      }
      if constexpr (AT == 2) {
#pragma unroll
        for (int l = 0; l < 4; ++l) {
          const int row = l * 32 + sr0;
          async16(pAl + (long)(bm + row) * lda + ka, &sAl[(l * 256 + tid) * 8]);
        }
      }
      if constexpr (BT == 2) {
#pragma unroll
        for (int l = 0; l < 4; ++l) {
          const int row = l * 32 + sr0;
          async16(pBl + (long)(bn + row) * ldbl + ka, &sBl[(l * 256 + tid) * 8]);
        }
      }
    }
    __syncthreads();

#pragma unroll
    for (int kk = 0; kk < 2; ++kk) {
      const int cs = cs0 ^ (kk * 32);
      vec8 ah[4], al[4];
#pragma unroll
      for (int i = 0; i < 4; ++i) {
        ah[i] = *(const vec8*)&sAh[(wm + i * 16 + l16) * BK + cs];
        if constexpr (AT == 2)
          al[i] = *(const vec8*)&sAl[(wm + i * 16 + l16) * BK + cs];
      }
#pragma unroll
      for (int j = 0; j < 4; ++j) {
        const vec8 bh = *(const vec8*)&sBh[(wn + j * 16 + l16) * BK + cs];
        vec8 bl;
        if constexpr (BT == 2)
          bl = *(const vec8*)&sBl[(wn + j * 16 + l16) * BK + cs];
#pragma unroll
        for (int i = 0; i < 4; ++i) {
          acc[i][j] = mfma8(ah[i], bh, acc[i][j]);
          if constexpr (BT == 2) acc[i][j] = mfma8(ah[i], bl, acc[i][j]);
          if constexpr (AT == 2) acc[i][j] = mfma8(al[i], bh, acc[i][j]);
        }
      }
    }
  }

  if constexpr (EPI == EPI_PAIR) {
    TO* Ch = (TO*)C0;
    TO* Cl = (TO*)C1;
#pragma unroll
    for (int i = 0; i < 4; ++i) {
      const int mb = bm + wm + i * 16 + quad * 4;
#pragma unroll
      for (int j = 0; j < 4; ++j) {
        const int n = bn + wn + j * 16 + l16;
#pragma unroll
        for (int r = 0; r < 4; ++r) {
          const float f = acc[i][j][r];
          const TO h = (TO)f;
          const long idx = (long)(mb + r) * ldc + n;
          Ch[idx] = h;
          Cl[idx] = (TO)(f - (float)h);
        }
      }
    }
  }
}

// One block per score row (2048 fp32). Writes normalized p * (1/sqrt(768)) as
// f16 IN-PLACE into the first quarter of the row's fp32 storage.
__global__ __launch_bounds__(256)
void softmax_kernel(float* __restrict__ sc) {
  __shared__ float red[4];
  float* srow = sc + (long)blockIdx.x * 2048;
  const int tid = threadIdx.x;
  const int wave = tid >> 6;
  const int lane = tid & 63;
  const float4 v0 = *(const float4*)(srow + tid * 4);
  const float4 v1 = *(const float4*)(srow + 1024 + tid * 4);
  float mx = fmaxf(fmaxf(fmaxf(v0.x, v0.y), fmaxf(v0.z, v0.w)),
                   fmaxf(fmaxf(v1.x, v1.y), fmaxf(v1.z, v1.w)));
#pragma unroll
  for (int o = 32; o >= 1; o >>= 1) mx = fmaxf(mx, __shfl_xor(mx, o));
  if (lane == 0) red[wave] = mx;
  __syncthreads();
  mx = fmaxf(fmaxf(red[0], red[1]), fmaxf(red[2], red[3]));
  const float e0 = exp2f((v0.x - mx) * LOG2E);
  const float e1 = exp2f((v0.y - mx) * LOG2E);
  const float e2 = exp2f((v0.z - mx) * LOG2E);
  const float e3 = exp2f((v0.w - mx) * LOG2E);
  const float e4 = exp2f((v1.x - mx) * LOG2E);
  const float e5 = exp2f((v1.y - mx) * LOG2E);
  const float e6 = exp2f((v1.z - mx) * LOG2E);
  const float e7 = exp2f((v1.w - mx) * LOG2E);
  float s = ((e0 + e1) + (e2 + e3)) + ((e4 + e5) + (e6 + e7));
#pragma unroll
  for (int o = 32; o >= 1; o >>= 1) s += __shfl_xor(s, o);
  __syncthreads();
  if (lane == 0) red[wave] = s;
  __syncthreads();
  s = red[0] + red[1] + red[2] + red[3];
  const float inv = 1.0f / (s * SQRT_E);
  f16* prow = (f16*)srow;
  union { f16 b[4]; uint2 u; } P;
  P.b[0] = (f16)(e0 * inv); P.b[1] = (f16)(e1 * inv);
  P.b[2] = (f16)(e2 * inv); P.b[3] = (f16)(e3 * inv);
  *(uint2*)(prow + tid * 4) = P.u;
  P.b[0] = (f16)(e4 * inv); P.b[1] = (f16)(e5 * inv);
  P.b[2] = (f16)(e6 * inv); P.b[3] = (f16)(e7 * inv);
  *(uint2*)(prow + 1024 + tid * 4) = P.u;
}

// Fused fp32 -> f16: x -> hi/lo pair; Wv -> single.
__global__ __launch_bounds__(256)
void split_all(const float4* __restrict__ x, const float4* __restrict__ wv,
               uint2* __restrict__ xh, uint2* __restrict__ xl,
               uint2* __restrict__ wvh) {
  constexpr int NX = 3145728;
  constexpr int NWV = 147456;
  const int i = blockIdx.x * 256 + threadIdx.x;
  float4 v;
  uint2 *dh, *dl;
  if (i < NX) {
    v = x[i]; dh = xh + i; dl = xl + i;
  } else {
    const int m = i - NX;
    if (m >= NWV) return;
    v = wv[m]; dh = wvh + m; dl = nullptr;
  }
  const f16 h0 = (f16)v.x, h1 = (f16)v.y, h2 = (f16)v.z, h3 = (f16)v.w;
  union { f16 b[4]; uint2 u; } P;
  P.b[0] = h0; P.b[1] = h1; P.b[2] = h2; P.b[3] = h3;
  *dh = P.u;
  if (dl != nullptr) {
    P.b[0] = (f16)(v.x - (float)h0);
    P.b[1] = (f16)(v.y - (float)h1);
    P.b[2] = (f16)(v.z - (float)h2);
    P.b[3] = (f16)(v.w - (float)h3);
    *dl = P.u;
  }
}

// Transpose 768x768 fp32 W[e][d] -> f16 hi/lo pair WT[d][e] (e contiguous).
__global__ __launch_bounds__(256)
void transpose_split(const float* __restrict__ Wq, const float* __restrict__ Wk,
                     f16* __restrict__ qTh, f16* __restrict__ qTl,
                     f16* __restrict__ kTh, f16* __restrict__ kTl) {
  __shared__ float tile[64][65];
  const float* src = blockIdx.z ? Wk : Wq;
  f16* dh = blockIdx.z ? kTh : qTh;
  f16* dl = blockIdx.z ? kTl : qTl;
  const int e0 = blockIdx.y * 64, d0 = blockIdx.x * 64;
  const int t = threadIdx.x;
  const int r = t >> 2;
  const int c4 = (t & 3) * 16;
  const float4* s4 = (const float4*)(src + (long)(e0 + r) * 768 + d0 + c4);
#pragma unroll
  for (int g = 0; g < 4; ++g) {
    const float4 v = s4[g];
    tile[r][c4 + g * 4 + 0] = v.x;
    tile[r][c4 + g * 4 + 1] = v.y;
    tile[r][c4 + g * 4 + 2] = v.z;
    tile[r][c4 + g * 4 + 3] = v.w;
  }
  __syncthreads();
  union { f16 b[8]; uint4 u; } H0, H1, L0, L1;
#pragma unroll
  for (int i = 0; i < 16; ++i) {
    const float v = tile[c4 + i][r];
    const f16 h = (f16)v;
    const f16 l = (f16)(v - (float)h);
    if (i < 8) { H0.b[i] = h; L0.b[i] = l; }
    else       { H1.b[i - 8] = h; L1.b[i - 8] = l; }
  }
  const long o = (long)(d0 + r) * 768 + e0 + c4;
  *(uint4*)(dh + o) = H0.u;  *(uint4*)(dh + o + 8) = H1.u;
  *(uint4*)(dl + o) = L0.u;  *(uint4*)(dl + o + 8) = L1.u;
}

extern "C" void kernel_launch(void* const* d_in, const int* in_sizes, int n_in,
                              void* d_out, int out_size, void* d_ws, size_t ws_size,
                              hipStream_t stream) {
  const float* x  = (const float*)d_in[0];
  const float* Wq = (const float*)d_in[1];
  const float* Wk = (const float*)d_in[2];
  const float* Wv = (const float*)d_in[3];
  float* out = (float*)d_out;
  char* ws = (char*)d_ws;

  // ---- workspace layout (bytes) ----
  const size_t SZ = 25165824;      // 16384*768*2
  f16* yh = (f16*)(ws + 0 * SZ);
  f16* xh = (f16*)(ws + 2 * SZ);
  f16* vT = (f16*)(ws + 3 * SZ);
  const size_t PERS = 4 * SZ;      // 100663296
  const size_t WT = 1179648;       // 768*768 f16
  f16* xl   = (f16*)(ws + PERS);
  f16* wqTh = (f16*)(ws + PERS + SZ);
  f16* wqTl = (f16*)(ws + PERS + SZ + 1 * WT);
  f16* wkTh = (f16*)(ws + PERS + SZ + 2 * WT);
  f16* wkTl = (f16*)(ws + PERS + SZ + 3 * WT);
  f16* mtH  = (f16*)(ws + PERS + SZ + 4 * WT);
  f16* mtL  = (f16*)(ws + PERS + SZ + 5 * WT);
  f16* wvh  = (f16*)(ws + PERS + SZ + 6 * WT);
  float* scores = (float*)(ws + PERS);

  long avail = (long)ws_size - (long)PERS;
  int nb = (int)(avail / 16777216);
  if (nb < 1) nb = 1;
  if (nb > 8) nb = 8;

  // ---- phase 1 ----
  split_all<<<12864, 256, 0, stream>>>(
      (const float4*)x, (const float4*)Wv, (uint2*)xh, (uint2*)xl, (uint2*)wvh);
  transpose_split<<<dim3(12, 12, 2), 256, 0, stream>>>(
      Wq, Wk, wqTh, wqTl, wkTh, wkTl);

  // M^T[d'][d] = sum_e WkT[d'][e] * WqT[d][e]  (3-term, f16 pair out)
  gemm_kernel<f16, f16, 2, 2, EPI_PAIR, 0><<<dim3(6, 6, 1), 256, 0, stream>>>(
      wkTh, wkTl, wqTh, wqTl, (void*)mtH, (void*)mtL,
      768, 768, 768, 768, 768, 0, 0, 0, 0, 0, 0);

  // y = (xh+xl) * MT_h^T : f16 hi only, 2-term, BK32 dbuf
  gemm_pipe<f16, f16, 128, 128, 32, 2, EPI_F16><<<768, 256, 0, stream>>>(
      xh, xl, mtH, (void*)yh, 768, 768, 768, 768, 0, 0, 0, 6, 128);

  // v = xh * Wv_h^T -> vT f16 transposed, 1-term, BK64 dbuf
  gemm_pipe<f16, f16, 128, 128, 64, 1, EPI_VT><<<768, 256, 0, stream>>>(
      xh, nullptr, wvh, (void*)vT, 768, 768, 768, 0, 0, 0, 0, 6, 128);

  // ---- phase 2: scores -> softmax -> PV ----
  const long RS = 1572864;   // 2048*768
  const long VTS = 1572864;  // 768*2048
  for (int b0 = 0; b0 < 8; b0 += nb) {
    const int nbg = (8 - b0 < nb) ? (8 - b0) : nb;
    // S = yh * xh^T : 256^2 ring, z-major (round-3 verified config)
    gemm_ring<f16, float, 1, EPI_F32, 0><<<64 * nbg, 512, 0, stream>>>(
        yh + (long)b0 * RS, nullptr, xh + (long)b0 * RS, (void*)scores,
        768, 768, 768, 2048, RS, RS, 4194304L, 8, 8, nbg);
    softmax_kernel<<<nbg * 2048, 256, 0, stream>>>(scores);
    // O = P * vT^T : 256^2 ring (P f16 rows in fp32 score rows, pitch 4096)
    gemm_ring<f16, float, 1, EPI_F32, 0><<<24 * nbg, 512, 0, stream>>>(
        (const f16*)scores, nullptr, vT + (long)b0 * VTS,
        (void*)(out + (long)b0 * 1572864),
        2048, 4096, 2048, 768, 8388608L, VTS, 1572864L, 3, 8, nbg);
  }
}